// Round 1
// baseline (2483.565 us; speedup 1.0000x reference)
//
#include <hip/hip_runtime.h>
#include <math.h>

#define B_  32
#define N_  512
#define H_  128
#define E_  131072
#define T_  9
#define BN_ (B_*N_)
#define EPB 32   // edges per block in edge kernel
#define NPB 8    // nodes per block in GRU kernel

// ---------------- type sort (counting sort by edge type) ----------------
// meta layout (ints): [0..8]=cnt, [9..17]=start, [18..26]=off(atomic), [27..36]=cumBlocks(10)

__global__ void count_types(const int* __restrict__ eids, int* __restrict__ meta) {
    int e = blockIdx.x * blockDim.x + threadIdx.x;
    if (e < E_) atomicAdd(&meta[eids[e * 4]], 1);
}

__global__ void scan_types(int* meta) {
    int s = 0;
    for (int t = 0; t < T_; ++t) { meta[9 + t] = s; meta[18 + t] = s; s += meta[t]; }
    int cb = 0;
    for (int t = 0; t < T_; ++t) { meta[27 + t] = cb; cb += (meta[t] + EPB - 1) / EPB; }
    meta[27 + T_] = cb;
}

__global__ void scatter_perm(const int* __restrict__ eids, int* __restrict__ meta,
                             int* __restrict__ perm) {
    int e = blockIdx.x * blockDim.x + threadIdx.x;
    if (e < E_) {
        int t = eids[e * 4];
        int pos = atomicAdd(&meta[18 + t], 1);
        perm[pos] = e;
    }
}

// ---------------- edge message + scatter-add ----------------
// One block = up to EPB edges, all the SAME type (guaranteed by segment-aligned blocks).
// Thread j computes output column j for all edges in the block.
__global__ __launch_bounds__(128) void edge_kernel(
    const float* __restrict__ h,     // (BN, H) current states
    const int*   __restrict__ eids,  // (E,4)
    const int*   __restrict__ perm,
    const int*   __restrict__ meta,
    const float* __restrict__ W,     // (T,H,H) this layer's slice
    const float* __restrict__ bias,  // (T,H)
    float*       __restrict__ agg)   // (BN,H) pre-zeroed
{
    __shared__ float src[EPB][H_];
    __shared__ int srcnode[EPB], tgt[EPB];
    __shared__ int info[3];
    const int j = threadIdx.x;

    if (j == 0) {
        int b = blockIdx.x;
        int nb = meta[27 + T_];
        if (b >= nb) {
            info[0] = -1;
        } else {
            int t = 0;
            while (b >= meta[27 + t + 1]) t++;
            int chunk = b - meta[27 + t];
            int c = meta[t] - chunk * EPB;
            info[0] = t;
            info[1] = meta[9 + t] + chunk * EPB;
            info[2] = (c > EPB) ? EPB : c;
        }
    }
    __syncthreads();
    const int t = info[0];
    if (t < 0) return;
    const int base = info[1], cnt = info[2];

    if (j < cnt) {
        int e  = perm[base + j];
        int eb = eids[e * 4 + 1];
        int es = eids[e * 4 + 2];
        int ed = eids[e * 4 + 3];
        srcnode[j] = eb * N_ + es;
        tgt[j]     = eb * N_ + ed;
    }
    __syncthreads();
    for (int e = 0; e < cnt; ++e) {
        src[e][j] = h[srcnode[e] * H_ + j];
    }
    __syncthreads();

    float acc[EPB];
#pragma unroll
    for (int e = 0; e < EPB; ++e) acc[e] = 0.f;

    const float* Wt = W + t * H_ * H_;
    for (int k = 0; k < H_; k += 4) {
        float w0 = Wt[(k + 0) * H_ + j];
        float w1 = Wt[(k + 1) * H_ + j];
        float w2 = Wt[(k + 2) * H_ + j];
        float w3 = Wt[(k + 3) * H_ + j];
#pragma unroll
        for (int e = 0; e < EPB; ++e) {
            float4 s4 = *reinterpret_cast<const float4*>(&src[e][k]);
            acc[e] = fmaf(s4.w, w3, fmaf(s4.z, w2, fmaf(s4.y, w1, fmaf(s4.x, w0, acc[e]))));
        }
    }

    const float bv = bias[t * H_ + j];
    for (int e = 0; e < cnt; ++e) {
        atomicAdd(&agg[tgt[e] * H_ + j], acc[e] + bv);
    }
}

// ---------------- GRU cell ----------------
// x = concat(res0?, res1?, agg). Thread j owns gate columns {j, j+128, j+256}.
// z-gate and r-gate accumulators are shared between x@W and h@U (z = sigmoid(xz+hz)).
template <int NSRC>
__global__ __launch_bounds__(128) void gru_kernel(
    const float* __restrict__ hcur,
    const float* __restrict__ res0,
    const float* __restrict__ res1,
    const float* __restrict__ agg,
    const float* __restrict__ W,      // (NSRC*H, 3H)
    const float* __restrict__ U,      // (H, 3H)
    const float* __restrict__ bgate,  // (2, 3H)
    float*       __restrict__ hout)
{
    __shared__ float xs[NPB][NSRC * H_];
    __shared__ float hs[NPB][H_];
    const int j = threadIdx.x;
    const int node0 = blockIdx.x * NPB;

    for (int e = 0; e < NPB; ++e) {
        int n = node0 + e;
        hs[e][j] = hcur[n * H_ + j];
        if constexpr (NSRC >= 2) xs[e][j] = res0[n * H_ + j];
        if constexpr (NSRC == 3) xs[e][H_ + j] = res1[n * H_ + j];
        xs[e][(NSRC - 1) * H_ + j] = agg[n * H_ + j];
    }
    __syncthreads();

    float accZ[NPB], accR[NPB], accC[NPB], accH[NPB];
#pragma unroll
    for (int e = 0; e < NPB; ++e) { accZ[e] = 0.f; accR[e] = 0.f; accC[e] = 0.f; accH[e] = 0.f; }

    // h @ U  -> hz, hr, hh
    for (int k = 0; k < H_; k += 4) {
        float uz0 = U[(k + 0) * 384 + j],        uz1 = U[(k + 1) * 384 + j];
        float uz2 = U[(k + 2) * 384 + j],        uz3 = U[(k + 3) * 384 + j];
        float ur0 = U[(k + 0) * 384 + 128 + j],  ur1 = U[(k + 1) * 384 + 128 + j];
        float ur2 = U[(k + 2) * 384 + 128 + j],  ur3 = U[(k + 3) * 384 + 128 + j];
        float uh0 = U[(k + 0) * 384 + 256 + j],  uh1 = U[(k + 1) * 384 + 256 + j];
        float uh2 = U[(k + 2) * 384 + 256 + j],  uh3 = U[(k + 3) * 384 + 256 + j];
#pragma unroll
        for (int e = 0; e < NPB; ++e) {
            float4 hv = *reinterpret_cast<const float4*>(&hs[e][k]);
            accZ[e] = fmaf(hv.x, uz0, fmaf(hv.y, uz1, fmaf(hv.z, uz2, fmaf(hv.w, uz3, accZ[e]))));
            accR[e] = fmaf(hv.x, ur0, fmaf(hv.y, ur1, fmaf(hv.z, ur2, fmaf(hv.w, ur3, accR[e]))));
            accH[e] = fmaf(hv.x, uh0, fmaf(hv.y, uh1, fmaf(hv.z, uh2, fmaf(hv.w, uh3, accH[e]))));
        }
    }
    // x @ W  -> xz, xr, xh
    for (int k = 0; k < NSRC * H_; k += 4) {
        float wz0 = W[(k + 0) * 384 + j],        wz1 = W[(k + 1) * 384 + j];
        float wz2 = W[(k + 2) * 384 + j],        wz3 = W[(k + 3) * 384 + j];
        float wr0 = W[(k + 0) * 384 + 128 + j],  wr1 = W[(k + 1) * 384 + 128 + j];
        float wr2 = W[(k + 2) * 384 + 128 + j],  wr3 = W[(k + 3) * 384 + 128 + j];
        float wh0 = W[(k + 0) * 384 + 256 + j],  wh1 = W[(k + 1) * 384 + 256 + j];
        float wh2 = W[(k + 2) * 384 + 256 + j],  wh3 = W[(k + 3) * 384 + 256 + j];
#pragma unroll
        for (int e = 0; e < NPB; ++e) {
            float4 xv = *reinterpret_cast<const float4*>(&xs[e][k]);
            accZ[e] = fmaf(xv.x, wz0, fmaf(xv.y, wz1, fmaf(xv.z, wz2, fmaf(xv.w, wz3, accZ[e]))));
            accR[e] = fmaf(xv.x, wr0, fmaf(xv.y, wr1, fmaf(xv.z, wr2, fmaf(xv.w, wr3, accR[e]))));
            accC[e] = fmaf(xv.x, wh0, fmaf(xv.y, wh1, fmaf(xv.z, wh2, fmaf(xv.w, wh3, accC[e]))));
        }
    }

    const float b0z = bgate[j],       b0r = bgate[128 + j],       b0h = bgate[256 + j];
    const float b1z = bgate[384 + j], b1r = bgate[384 + 128 + j], b1h = bgate[384 + 256 + j];
#pragma unroll
    for (int e = 0; e < NPB; ++e) {
        int n = node0 + e;
        float z = 1.f / (1.f + expf(-(accZ[e] + b0z + b1z)));
        float r = 1.f / (1.f + expf(-(accR[e] + b0r + b1r)));
        float cand = tanhf(accC[e] + b0h + r * (accH[e] + b1h));
        float hv = hs[e][j];
        hout[n * H_ + j] = z * hv + (1.f - z) * cand;
    }
}

// ---------------- host orchestration ----------------
extern "C" void kernel_launch(void* const* d_in, const int* in_sizes, int n_in,
                              void* d_out, int out_size, void* d_ws, size_t ws_size,
                              hipStream_t stream) {
    const float* states = (const float*)d_in[0];
    const int*   eids   = (const int*)  d_in[1];
    const float* tw     = (const float*)d_in[2];   // (4,T,H,H)
    const float* tb     = (const float*)d_in[3];   // (4,T,H)
    const float* gW[4]  = { (const float*)d_in[4],  (const float*)d_in[7],
                            (const float*)d_in[10], (const float*)d_in[13] };
    const float* gU[4]  = { (const float*)d_in[5],  (const float*)d_in[8],
                            (const float*)d_in[11], (const float*)d_in[14] };
    const float* gb[4]  = { (const float*)d_in[6],  (const float*)d_in[9],
                            (const float*)d_in[12], (const float*)d_in[15] };
    float* out = (float*)d_out;

    char* ws = (char*)d_ws;
    float* bufA = (float*)ws; ws += (size_t)BN_ * H_ * 4;
    float* bufB = (float*)ws; ws += (size_t)BN_ * H_ * 4;
    float* bufC = (float*)ws; ws += (size_t)BN_ * H_ * 4;   // holds h0 (end of layer 0)
    float* agg  = (float*)ws; ws += (size_t)BN_ * H_ * 4;
    int*   perm = (int*)ws;   ws += (size_t)E_ * 4;
    int*   meta = (int*)ws;   ws += 64 * 4;

    // type-sort edges (per call; cheap, deterministic up to atomic order which
    // only permutes within a type segment — scatter-add is order-insensitive)
    hipMemsetAsync(meta, 0, 40 * sizeof(int), stream);
    count_types<<<(E_ + 255) / 256, 256, 0, stream>>>(eids, meta);
    scan_types<<<1, 1, 0, stream>>>(meta);
    scatter_perm<<<(E_ + 255) / 256, 256, 0, stream>>>(eids, meta, perm);

    // step schedule: layers [0,0,0, 1, 2,2,2, 3]
    const int layer_of[8] = {0, 0, 0, 1, 2, 2, 2, 3};
    float* target[8] = {bufA, bufB, bufC, bufA, bufB, bufA, bufB, out};

    const float* cur = states;
    const int edge_grid = E_ / EPB + T_;
    const int gru_grid  = BN_ / NPB;

    for (int s = 0; s < 8; ++s) {
        const int l = layer_of[s];
        hipMemsetAsync(agg, 0, (size_t)BN_ * H_ * 4, stream);
        edge_kernel<<<edge_grid, 128, 0, stream>>>(
            cur, eids, perm, meta, tw + (size_t)l * T_ * H_ * H_, tb + (size_t)l * T_ * H_, agg);
        float* nxt = target[s];
        if (l == 0 || l == 2) {
            gru_kernel<1><<<gru_grid, 128, 0, stream>>>(cur, nullptr, nullptr, agg,
                                                        gW[l], gU[l], gb[l], nxt);
        } else if (l == 1) {
            gru_kernel<2><<<gru_grid, 128, 0, stream>>>(cur, states, nullptr, agg,
                                                        gW[1], gU[1], gb[1], nxt);
        } else {
            gru_kernel<3><<<gru_grid, 128, 0, stream>>>(cur, states, bufC, agg,
                                                        gW[3], gU[3], gb[3], nxt);
        }
        cur = nxt;
    }
}

// Round 2
// 1885.690 us; speedup vs baseline: 1.3171x; 1.3171x over previous
//
#include <hip/hip_runtime.h>
#include <math.h>

#define B_  32
#define N_  512
#define H_  128
#define E_  131072
#define T_  9
#define BN_ (B_*N_)
#define EPB 32   // edges per block in edge GEMM
#define NPB 16   // nodes per block in GRU kernel

// meta layout (ints): [0..8]=cnt, [9..17]=start, [18..26]=off(atomic), [27..36]=cumBlocks(10)

// ---------------- type sort (LDS-histogram counting sort) ----------------
__global__ void count_types(const int* __restrict__ eids, int* __restrict__ meta) {
    __shared__ int lc[T_];
    if (threadIdx.x < T_) lc[threadIdx.x] = 0;
    __syncthreads();
    int e = blockIdx.x * 256 + threadIdx.x;
    if (e < E_) atomicAdd(&lc[eids[e * 4]], 1);
    __syncthreads();
    if (threadIdx.x < T_ && lc[threadIdx.x]) atomicAdd(&meta[threadIdx.x], lc[threadIdx.x]);
}

__global__ void scan_types(int* meta) {
    int s = 0;
    for (int t = 0; t < T_; ++t) { meta[9 + t] = s; meta[18 + t] = s; s += meta[t]; }
    int cb = 0;
    for (int t = 0; t < T_; ++t) { meta[27 + t] = cb; cb += (meta[t] + EPB - 1) / EPB; }
    meta[27 + T_] = cb;
}

__global__ void scatter_types(const int* __restrict__ eids, int* __restrict__ meta,
                              int* __restrict__ perm) {
    __shared__ int lc[T_], lbase[T_];
    if (threadIdx.x < T_) lc[threadIdx.x] = 0;
    __syncthreads();
    int e = blockIdx.x * 256 + threadIdx.x;
    int t = 0, lp = 0;
    if (e < E_) { t = eids[e * 4]; lp = atomicAdd(&lc[t], 1); }
    __syncthreads();
    if (threadIdx.x < T_ && lc[threadIdx.x])
        lbase[threadIdx.x] = atomicAdd(&meta[18 + threadIdx.x], lc[threadIdx.x]);
    __syncthreads();
    if (e < E_) perm[lbase[t] + lp] = e;
}

// ---------------- target sort (16384 bins; low contention) ----------------
__global__ void hist_tgt(const int* __restrict__ eids, int* __restrict__ tcnt) {
    int e = blockIdx.x * 256 + threadIdx.x;
    if (e < E_) {
        int tgt = eids[e * 4 + 1] * N_ + eids[e * 4 + 3];
        atomicAdd(&tcnt[tgt], 1);
    }
}

__global__ void scan_tgt(const int* __restrict__ tcnt, int* __restrict__ tstart,
                         int* __restrict__ toff) {
    __shared__ int bs[256];
    const int tid = threadIdx.x;
    const int chunk = BN_ / 256;   // 64
    const int base = tid * chunk;
    int s = 0;
    for (int i = 0; i < chunk; ++i) s += tcnt[base + i];
    bs[tid] = s;
    __syncthreads();
    if (tid == 0) { int acc = 0; for (int i = 0; i < 256; ++i) { int v = bs[i]; bs[i] = acc; acc += v; } }
    __syncthreads();
    int acc = bs[tid];
    for (int i = 0; i < chunk; ++i) {
        int v = tcnt[base + i];
        tstart[base + i] = acc; toff[base + i] = acc; acc += v;
    }
    if (tid == 255) tstart[BN_] = E_;
}

__global__ void scatter_tgt(const int* __restrict__ eids, int* __restrict__ toff,
                            int* __restrict__ tperm) {
    int e = blockIdx.x * 256 + threadIdx.x;
    if (e < E_) {
        int tgt = eids[e * 4 + 1] * N_ + eids[e * 4 + 3];
        int pos = atomicAdd(&toff[tgt], 1);
        tperm[pos] = e;
    }
}

// ---------------- edge message GEMM (type-sorted, no atomics) ----------------
// One block = up to EPB edges of the SAME type. Thread j = output column j.
// Writes msg[e][j] = (src @ W[t])[j] + bias[t][j], indexed by ORIGINAL edge id.
__global__ __launch_bounds__(128) void edge_gemm(
    const float* __restrict__ h,
    const int*   __restrict__ eids,
    const int*   __restrict__ perm,
    const int*   __restrict__ meta,
    const float* __restrict__ W,     // (T,H,H) this layer
    const float* __restrict__ bias,  // (T,H)
    float*       __restrict__ msg)   // (E,H)
{
    __shared__ float src[EPB][H_];
    __shared__ int srcnode[EPB], eidL[EPB];
    __shared__ int info[3];
    const int j = threadIdx.x;

    if (j == 0) {
        int b = blockIdx.x;
        int nb = meta[27 + T_];
        if (b >= nb) info[0] = -1;
        else {
            int t = 0;
            while (b >= meta[27 + t + 1]) t++;
            int chunk = b - meta[27 + t];
            int c = meta[t] - chunk * EPB;
            info[0] = t;
            info[1] = meta[9 + t] + chunk * EPB;
            info[2] = (c > EPB) ? EPB : c;
        }
    }
    __syncthreads();
    const int t = info[0];
    if (t < 0) return;
    const int base = info[1], cnt = info[2];

    if (j < cnt) {
        int e = perm[base + j];
        int eb = eids[e * 4 + 1];
        int es = eids[e * 4 + 2];
        srcnode[j] = eb * N_ + es;
        eidL[j] = e;
    }
    __syncthreads();
    for (int e = 0; e < cnt; ++e) src[e][j] = h[(size_t)srcnode[e] * H_ + j];
    __syncthreads();

    float acc[EPB];
#pragma unroll
    for (int e = 0; e < EPB; ++e) acc[e] = 0.f;

    const float* Wt = W + (size_t)t * H_ * H_;
    for (int k = 0; k < H_; k += 4) {
        float w0 = Wt[(k + 0) * H_ + j];
        float w1 = Wt[(k + 1) * H_ + j];
        float w2 = Wt[(k + 2) * H_ + j];
        float w3 = Wt[(k + 3) * H_ + j];
#pragma unroll
        for (int e = 0; e < EPB; ++e) {
            float4 s4 = *reinterpret_cast<const float4*>(&src[e][k]);
            acc[e] = fmaf(s4.w, w3, fmaf(s4.z, w2, fmaf(s4.y, w1, fmaf(s4.x, w0, acc[e]))));
        }
    }

    const float bv = bias[t * H_ + j];
    for (int e = 0; e < cnt; ++e)
        msg[(size_t)eidL[e] * H_ + j] = acc[e] + bv;
}

// ---------------- segmented aggregation (target-sorted, no atomics) ----------------
__global__ __launch_bounds__(256) void aggregate(
    const float* __restrict__ msg,
    const int*   __restrict__ tperm,
    const int*   __restrict__ tstart,
    float*       __restrict__ agg)
{
    const int j = threadIdx.x & 127;
    const int n = blockIdx.x * 2 + (threadIdx.x >> 7);
    const int s = tstart[n], e_end = tstart[n + 1];
    float acc = 0.f;
    for (int i = s; i < e_end; ++i) {
        int e = tperm[i];
        acc += msg[(size_t)e * H_ + j];
    }
    agg[(size_t)n * H_ + j] = acc;
}

// ---------------- GRU cell ----------------
template <int NSRC>
__global__ __launch_bounds__(128) void gru_kernel(
    const float* __restrict__ hcur,
    const float* __restrict__ res0,
    const float* __restrict__ res1,
    const float* __restrict__ agg,
    const float* __restrict__ W,      // (NSRC*H, 3H)
    const float* __restrict__ U,      // (H, 3H)
    const float* __restrict__ bgate,  // (2, 3H)
    float*       __restrict__ hout)
{
    __shared__ float xs[NPB][NSRC * H_];
    __shared__ float hs[NPB][H_];
    const int j = threadIdx.x;
    const int node0 = blockIdx.x * NPB;

    for (int e = 0; e < NPB; ++e) {
        int n = node0 + e;
        hs[e][j] = hcur[(size_t)n * H_ + j];
        if constexpr (NSRC >= 2) xs[e][j] = res0[(size_t)n * H_ + j];
        if constexpr (NSRC == 3) xs[e][H_ + j] = res1[(size_t)n * H_ + j];
        xs[e][(NSRC - 1) * H_ + j] = agg[(size_t)n * H_ + j];
    }
    __syncthreads();

    float accZ[NPB], accR[NPB], accC[NPB], accH[NPB];
#pragma unroll
    for (int e = 0; e < NPB; ++e) { accZ[e] = 0.f; accR[e] = 0.f; accC[e] = 0.f; accH[e] = 0.f; }

    // h @ U -> hz, hr, hh
    for (int k = 0; k < H_; k += 4) {
        float uz0 = U[(k + 0) * 384 + j],        uz1 = U[(k + 1) * 384 + j];
        float uz2 = U[(k + 2) * 384 + j],        uz3 = U[(k + 3) * 384 + j];
        float ur0 = U[(k + 0) * 384 + 128 + j],  ur1 = U[(k + 1) * 384 + 128 + j];
        float ur2 = U[(k + 2) * 384 + 128 + j],  ur3 = U[(k + 3) * 384 + 128 + j];
        float uh0 = U[(k + 0) * 384 + 256 + j],  uh1 = U[(k + 1) * 384 + 256 + j];
        float uh2 = U[(k + 2) * 384 + 256 + j],  uh3 = U[(k + 3) * 384 + 256 + j];
#pragma unroll
        for (int e = 0; e < NPB; ++e) {
            float4 hv = *reinterpret_cast<const float4*>(&hs[e][k]);
            accZ[e] = fmaf(hv.x, uz0, fmaf(hv.y, uz1, fmaf(hv.z, uz2, fmaf(hv.w, uz3, accZ[e]))));
            accR[e] = fmaf(hv.x, ur0, fmaf(hv.y, ur1, fmaf(hv.z, ur2, fmaf(hv.w, ur3, accR[e]))));
            accH[e] = fmaf(hv.x, uh0, fmaf(hv.y, uh1, fmaf(hv.z, uh2, fmaf(hv.w, uh3, accH[e]))));
        }
    }
    // x @ W -> xz, xr, xh
    for (int k = 0; k < NSRC * H_; k += 4) {
        float wz0 = W[(k + 0) * 384 + j],        wz1 = W[(k + 1) * 384 + j];
        float wz2 = W[(k + 2) * 384 + j],        wz3 = W[(k + 3) * 384 + j];
        float wr0 = W[(k + 0) * 384 + 128 + j],  wr1 = W[(k + 1) * 384 + 128 + j];
        float wr2 = W[(k + 2) * 384 + 128 + j],  wr3 = W[(k + 3) * 384 + 128 + j];
        float wh0 = W[(k + 0) * 384 + 256 + j],  wh1 = W[(k + 1) * 384 + 256 + j];
        float wh2 = W[(k + 2) * 384 + 256 + j],  wh3 = W[(k + 3) * 384 + 256 + j];
#pragma unroll
        for (int e = 0; e < NPB; ++e) {
            float4 xv = *reinterpret_cast<const float4*>(&xs[e][k]);
            accZ[e] = fmaf(xv.x, wz0, fmaf(xv.y, wz1, fmaf(xv.z, wz2, fmaf(xv.w, wz3, accZ[e]))));
            accR[e] = fmaf(xv.x, wr0, fmaf(xv.y, wr1, fmaf(xv.z, wr2, fmaf(xv.w, wr3, accR[e]))));
            accC[e] = fmaf(xv.x, wh0, fmaf(xv.y, wh1, fmaf(xv.z, wh2, fmaf(xv.w, wh3, accC[e]))));
        }
    }

    const float b0z = bgate[j],       b0r = bgate[128 + j],       b0h = bgate[256 + j];
    const float b1z = bgate[384 + j], b1r = bgate[384 + 128 + j], b1h = bgate[384 + 256 + j];
#pragma unroll
    for (int e = 0; e < NPB; ++e) {
        int n = node0 + e;
        float z = 1.f / (1.f + expf(-(accZ[e] + b0z + b1z)));
        float r = 1.f / (1.f + expf(-(accR[e] + b0r + b1r)));
        float cand = tanhf(accC[e] + b0h + r * (accH[e] + b1h));
        float hv = hs[e][j];
        hout[(size_t)n * H_ + j] = z * hv + (1.f - z) * cand;
    }
}

// ---------------- host orchestration ----------------
extern "C" void kernel_launch(void* const* d_in, const int* in_sizes, int n_in,
                              void* d_out, int out_size, void* d_ws, size_t ws_size,
                              hipStream_t stream) {
    const float* states = (const float*)d_in[0];
    const int*   eids   = (const int*)  d_in[1];
    const float* tw     = (const float*)d_in[2];   // (4,T,H,H)
    const float* tb     = (const float*)d_in[3];   // (4,T,H)
    const float* gW[4]  = { (const float*)d_in[4],  (const float*)d_in[7],
                            (const float*)d_in[10], (const float*)d_in[13] };
    const float* gU[4]  = { (const float*)d_in[5],  (const float*)d_in[8],
                            (const float*)d_in[11], (const float*)d_in[14] };
    const float* gb[4]  = { (const float*)d_in[6],  (const float*)d_in[9],
                            (const float*)d_in[12], (const float*)d_in[15] };
    float* out = (float*)d_out;

    char* ws = (char*)d_ws;
    float* bufA = (float*)ws; ws += (size_t)BN_ * H_ * 4;
    float* bufB = (float*)ws; ws += (size_t)BN_ * H_ * 4;
    float* bufC = (float*)ws; ws += (size_t)BN_ * H_ * 4;   // final layer-0 state (res1 of layer 3)
    float* agg  = (float*)ws; ws += (size_t)BN_ * H_ * 4;
    float* msg  = (float*)ws; ws += (size_t)E_ * H_ * 4;    // 64 MB
    int*   perm  = (int*)ws;  ws += (size_t)E_ * 4;
    int*   tperm = (int*)ws;  ws += (size_t)E_ * 4;
    int*   tcnt  = (int*)ws;  ws += (size_t)BN_ * 4;
    int*   toff  = (int*)ws;  ws += (size_t)BN_ * 4;
    int*   tstart= (int*)ws;  ws += (size_t)(BN_ + 1) * 4;
    int*   meta  = (int*)ws;  ws += 64 * 4;

    // ---- one-time sorts (per call) ----
    hipMemsetAsync(meta, 0, 40 * sizeof(int), stream);
    hipMemsetAsync(tcnt, 0, BN_ * sizeof(int), stream);
    count_types<<<(E_ + 255) / 256, 256, 0, stream>>>(eids, meta);
    hist_tgt   <<<(E_ + 255) / 256, 256, 0, stream>>>(eids, tcnt);
    scan_types <<<1, 1, 0, stream>>>(meta);
    scan_tgt   <<<1, 256, 0, stream>>>(tcnt, tstart, toff);
    scatter_types<<<(E_ + 255) / 256, 256, 0, stream>>>(eids, meta, perm);
    scatter_tgt  <<<(E_ + 255) / 256, 256, 0, stream>>>(eids, toff, tperm);

    // step schedule: layers [0,0,0, 1, 2,2,2, 3]
    const int layer_of[8] = {0, 0, 0, 1, 2, 2, 2, 3};
    float* target[8] = {bufA, bufB, bufC, bufA, bufB, bufA, bufB, out};

    const float* cur = states;
    const int edge_grid = E_ / EPB + T_;
    const int gru_grid  = BN_ / NPB;

    for (int s = 0; s < 8; ++s) {
        const int l = layer_of[s];
        edge_gemm<<<edge_grid, 128, 0, stream>>>(
            cur, eids, perm, meta, tw + (size_t)l * T_ * H_ * H_, tb + (size_t)l * T_ * H_, msg);
        aggregate<<<BN_ / 2, 256, 0, stream>>>(msg, tperm, tstart, agg);
        float* nxt = target[s];
        if (l == 0 || l == 2) {
            gru_kernel<1><<<gru_grid, 128, 0, stream>>>(cur, nullptr, nullptr, agg,
                                                        gW[l], gU[l], gb[l], nxt);
        } else if (l == 1) {
            gru_kernel<2><<<gru_grid, 128, 0, stream>>>(cur, states, nullptr, agg,
                                                        gW[1], gU[1], gb[1], nxt);
        } else {
            gru_kernel<3><<<gru_grid, 128, 0, stream>>>(cur, states, bufC, agg,
                                                        gW[3], gU[3], gb[3], nxt);
        }
        cur = nxt;
    }
}

// Round 3
// 1761.841 us; speedup vs baseline: 1.4096x; 1.0703x over previous
//
#include <hip/hip_runtime.h>
#include <math.h>

#define B_  32
#define N_  512
#define H_  128
#define E_  131072
#define T_  9
#define BN_ (B_*N_)
#define EPB 32   // edges per block in edge GEMM

// meta layout (ints): [0..8]=cnt, [9..17]=start, [18..26]=off(atomic), [27..36]=cumBlocks(10)

// ---------------- type sort (LDS-histogram counting sort) ----------------
__global__ void count_types(const int* __restrict__ eids, int* __restrict__ meta) {
    __shared__ int lc[T_];
    if (threadIdx.x < T_) lc[threadIdx.x] = 0;
    __syncthreads();
    int e = blockIdx.x * 256 + threadIdx.x;
    if (e < E_) atomicAdd(&lc[eids[e * 4]], 1);
    __syncthreads();
    if (threadIdx.x < T_ && lc[threadIdx.x]) atomicAdd(&meta[threadIdx.x], lc[threadIdx.x]);
}

__global__ void scan_types(int* meta) {
    int s = 0;
    for (int t = 0; t < T_; ++t) { meta[9 + t] = s; meta[18 + t] = s; s += meta[t]; }
    int cb = 0;
    for (int t = 0; t < T_; ++t) { meta[27 + t] = cb; cb += (meta[t] + EPB - 1) / EPB; }
    meta[27 + T_] = cb;
}

__global__ void scatter_types(const int* __restrict__ eids, int* __restrict__ meta,
                              int* __restrict__ perm) {
    __shared__ int lc[T_], lbase[T_];
    if (threadIdx.x < T_) lc[threadIdx.x] = 0;
    __syncthreads();
    int e = blockIdx.x * 256 + threadIdx.x;
    int t = 0, lp = 0;
    if (e < E_) { t = eids[e * 4]; lp = atomicAdd(&lc[t], 1); }
    __syncthreads();
    if (threadIdx.x < T_ && lc[threadIdx.x])
        lbase[threadIdx.x] = atomicAdd(&meta[18 + threadIdx.x], lc[threadIdx.x]);
    __syncthreads();
    if (e < E_) perm[lbase[t] + lp] = e;
}

// ---------------- target sort (16384 bins; emits rank[e]) ----------------
__global__ void hist_tgt(const int* __restrict__ eids, int* __restrict__ tcnt) {
    int e = blockIdx.x * 256 + threadIdx.x;
    if (e < E_) {
        int tgt = eids[e * 4 + 1] * N_ + eids[e * 4 + 3];
        atomicAdd(&tcnt[tgt], 1);
    }
}

__global__ void scan_tgt(const int* __restrict__ tcnt, int* __restrict__ tstart,
                         int* __restrict__ toff) {
    __shared__ int bs[256];
    const int tid = threadIdx.x;
    const int chunk = BN_ / 256;   // 64
    const int base = tid * chunk;
    int s = 0;
    for (int i = 0; i < chunk; ++i) s += tcnt[base + i];
    bs[tid] = s;
    __syncthreads();
    if (tid == 0) { int acc = 0; for (int i = 0; i < 256; ++i) { int v = bs[i]; bs[i] = acc; acc += v; } }
    __syncthreads();
    int acc = bs[tid];
    for (int i = 0; i < chunk; ++i) {
        int v = tcnt[base + i];
        tstart[base + i] = acc; toff[base + i] = acc; acc += v;
    }
    if (tid == 255) tstart[BN_] = E_;
}

__global__ void scatter_tgt(const int* __restrict__ eids, int* __restrict__ toff,
                            int* __restrict__ rank) {
    int e = blockIdx.x * 256 + threadIdx.x;
    if (e < E_) {
        int tgt = eids[e * 4 + 1] * N_ + eids[e * 4 + 3];
        int pos = atomicAdd(&toff[tgt], 1);
        rank[e] = pos;
    }
}

// ---------------- edge message GEMM (type-sorted; writes in target-rank order) ----------------
__global__ __launch_bounds__(128) void edge_gemm(
    const float* __restrict__ h,
    const int*   __restrict__ eids,
    const int*   __restrict__ perm,
    const int*   __restrict__ rank,
    const int*   __restrict__ meta,
    const float* __restrict__ W,     // (T,H,H) this layer
    const float* __restrict__ bias,  // (T,H)
    float*       __restrict__ msg)   // (E,H) in target-sorted order
{
    __shared__ float src[EPB][H_];
    __shared__ int srcnode[EPB], outrow[EPB];
    __shared__ int info[3];
    const int j = threadIdx.x;

    if (j == 0) {
        int b = blockIdx.x;
        int nb = meta[27 + T_];
        if (b >= nb) info[0] = -1;
        else {
            int t = 0;
            while (b >= meta[27 + t + 1]) t++;
            int chunk = b - meta[27 + t];
            int c = meta[t] - chunk * EPB;
            info[0] = t;
            info[1] = meta[9 + t] + chunk * EPB;
            info[2] = (c > EPB) ? EPB : c;
        }
    }
    __syncthreads();
    const int t = info[0];
    if (t < 0) return;
    const int base = info[1], cnt = info[2];

    if (j < cnt) {
        int e = perm[base + j];
        int eb = eids[e * 4 + 1];
        int es = eids[e * 4 + 2];
        srcnode[j] = eb * N_ + es;
        outrow[j]  = rank[e];
    }
    __syncthreads();
    for (int e = 0; e < cnt; ++e) src[e][j] = h[(size_t)srcnode[e] * H_ + j];
    __syncthreads();

    float acc[EPB];
#pragma unroll
    for (int e = 0; e < EPB; ++e) acc[e] = 0.f;

    const float* Wt = W + (size_t)t * H_ * H_;
    for (int k = 0; k < H_; k += 4) {
        float w0 = Wt[(k + 0) * H_ + j];
        float w1 = Wt[(k + 1) * H_ + j];
        float w2 = Wt[(k + 2) * H_ + j];
        float w3 = Wt[(k + 3) * H_ + j];
#pragma unroll
        for (int e = 0; e < EPB; ++e) {
            float4 s4 = *reinterpret_cast<const float4*>(&src[e][k]);
            acc[e] = fmaf(s4.w, w3, fmaf(s4.z, w2, fmaf(s4.y, w1, fmaf(s4.x, w0, acc[e]))));
        }
    }

    const float bv = bias[t * H_ + j];
    for (int e = 0; e < cnt; ++e)
        msg[(size_t)outrow[e] * H_ + j] = acc[e] + bv;
}

// ---------------- segmented aggregation (contiguous reads, no atomics) ----------------
__global__ __launch_bounds__(256) void aggregate(
    const float* __restrict__ msg,
    const int*   __restrict__ tstart,
    float*       __restrict__ agg)
{
    const int j = threadIdx.x & 127;
    const int n = blockIdx.x * 2 + (threadIdx.x >> 7);
    const int s = tstart[n], e_end = tstart[n + 1];
    float acc = 0.f;
    for (int i = s; i < e_end; ++i) acc += msg[(size_t)i * H_ + j];
    agg[(size_t)n * H_ + j] = acc;
}

// ---------------- GRU gates GEMM ----------------
// gates (BN,512) = [ zpre | rpre | xh | hh ], zpre/rpre over full K, xh over x-rows,
// hh over h-rows. A = concat(x-sources..., h) selected per 128-row segment.
#define GM 64
#define GN 64
#define GK 16
__global__ __launch_bounds__(256) void gates_gemm(
    const float* __restrict__ s0, const float* __restrict__ s1,
    const float* __restrict__ s2, const float* __restrict__ s3,
    const float* __restrict__ W,  // (nsrc*128, 384)
    const float* __restrict__ U,  // (128, 384)
    int nsrc,
    float* __restrict__ gates)
{
    __shared__ float As[GK][GM + 4];
    __shared__ float Bs[GK][GN];
    const int tid = threadIdx.x;
    const int m0 = blockIdx.x * GM;
    const int by = blockIdx.y;
    const int n0 = by * GN;
    const int Kx = nsrc * 128;
    int k_lo, k_hi;
    if (by < 4)      { k_lo = 0;  k_hi = Kx + 128; }
    else if (by < 6) { k_lo = 0;  k_hi = Kx; }
    else             { k_lo = Kx; k_hi = Kx + 128; }

    const float* srcs[4] = {s0, s1, s2, s3};

    float acc[4][4] = {};
    const int tm = (tid & 15) * 4;
    const int tn = (tid >> 4) * 4;
    const int ak = tid & 15;    // k within tile (A load)
    const int am = tid >> 4;    // row group (A load)
    const int bn = tid & 63;    // col (B load)
    const int bk = tid >> 6;    // k group (B load)

    for (int k0 = k_lo; k0 < k_hi; k0 += GK) {
        const float* sp = srcs[k0 >> 7];
        const int kc = (k0 & 127) + ak;
#pragma unroll
        for (int r = 0; r < 4; ++r) {
            int m = am + r * 16;
            As[ak][m] = sp[(size_t)(m0 + m) * H_ + kc];
        }
#pragma unroll
        for (int r = 0; r < 4; ++r) {
            int kk = bk + r * 4;
            int k = k0 + kk;
            float v;
            if (by < 6) v = (k < Kx) ? W[(size_t)k * 384 + n0 + bn]
                                     : U[(size_t)(k - Kx) * 384 + n0 + bn];
            else        v = U[(size_t)(k - Kx) * 384 + (n0 - 128) + bn];
            Bs[kk][bn] = v;
        }
        __syncthreads();
#pragma unroll
        for (int kk = 0; kk < GK; ++kk) {
            float a[4], b[4];
#pragma unroll
            for (int i = 0; i < 4; ++i) a[i] = As[kk][tm + i];
#pragma unroll
            for (int i = 0; i < 4; ++i) b[i] = Bs[kk][tn + i];
#pragma unroll
            for (int i = 0; i < 4; ++i)
#pragma unroll
                for (int jj = 0; jj < 4; ++jj)
                    acc[i][jj] = fmaf(a[i], b[jj], acc[i][jj]);
        }
        __syncthreads();
    }
#pragma unroll
    for (int i = 0; i < 4; ++i) {
        float4 v = make_float4(acc[i][0], acc[i][1], acc[i][2], acc[i][3]);
        *reinterpret_cast<float4*>(&gates[(size_t)(m0 + tm + i) * 512 + n0 + tn]) = v;
    }
}

// ---------------- GRU elementwise ----------------
__global__ __launch_bounds__(256) void gru_elem(
    const float* __restrict__ gates,
    const float* __restrict__ hcur,
    const float* __restrict__ b,     // (2,384) flat
    float*       __restrict__ hout)
{
    int idx = blockIdx.x * 256 + threadIdx.x;
    int n = idx >> 7, j = idx & 127;
    const float* g = gates + (size_t)n * 512;
    float zpre = g[j]       + b[j]       + b[384 + j];
    float rpre = g[128 + j] + b[128 + j] + b[512 + j];
    float xh   = g[256 + j] + b[256 + j];
    float hh   = g[384 + j] + b[640 + j];
    float z = 1.f / (1.f + expf(-zpre));
    float r = 1.f / (1.f + expf(-rpre));
    float cand = tanhf(xh + r * hh);
    float h = hcur[idx];
    hout[idx] = z * h + (1.f - z) * cand;
}

// ---------------- host orchestration ----------------
extern "C" void kernel_launch(void* const* d_in, const int* in_sizes, int n_in,
                              void* d_out, int out_size, void* d_ws, size_t ws_size,
                              hipStream_t stream) {
    const float* states = (const float*)d_in[0];
    const int*   eids   = (const int*)  d_in[1];
    const float* tw     = (const float*)d_in[2];   // (4,T,H,H)
    const float* tb     = (const float*)d_in[3];   // (4,T,H)
    const float* gW[4]  = { (const float*)d_in[4],  (const float*)d_in[7],
                            (const float*)d_in[10], (const float*)d_in[13] };
    const float* gU[4]  = { (const float*)d_in[5],  (const float*)d_in[8],
                            (const float*)d_in[11], (const float*)d_in[14] };
    const float* gb[4]  = { (const float*)d_in[6],  (const float*)d_in[9],
                            (const float*)d_in[12], (const float*)d_in[15] };
    float* out = (float*)d_out;

    char* ws = (char*)d_ws;
    float* bufA = (float*)ws; ws += (size_t)BN_ * H_ * 4;
    float* bufB = (float*)ws; ws += (size_t)BN_ * H_ * 4;
    float* bufC = (float*)ws; ws += (size_t)BN_ * H_ * 4;   // final layer-0 state
    float* agg  = (float*)ws; ws += (size_t)BN_ * H_ * 4;
    float* msg  = (float*)ws; ws += (size_t)E_ * H_ * 4;    // 64 MB; gates aliases it
    int*   perm  = (int*)ws;  ws += (size_t)E_ * 4;
    int*   rank  = (int*)ws;  ws += (size_t)E_ * 4;
    int*   tcnt  = (int*)ws;  ws += (size_t)BN_ * 4;
    int*   toff  = (int*)ws;  ws += (size_t)BN_ * 4;
    int*   tstart= (int*)ws;  ws += (size_t)(BN_ + 1) * 4;
    int*   meta  = (int*)ws;  ws += 64 * 4;
    float* gates = msg;   // msg is dead once aggregate finishes; reuse (needs 33.5MB < 64MB)

    // ---- one-time sorts ----
    hipMemsetAsync(meta, 0, 40 * sizeof(int), stream);
    hipMemsetAsync(tcnt, 0, BN_ * sizeof(int), stream);
    count_types<<<(E_ + 255) / 256, 256, 0, stream>>>(eids, meta);
    hist_tgt   <<<(E_ + 255) / 256, 256, 0, stream>>>(eids, tcnt);
    scan_types <<<1, 1, 0, stream>>>(meta);
    scan_tgt   <<<1, 256, 0, stream>>>(tcnt, tstart, toff);
    scatter_types<<<(E_ + 255) / 256, 256, 0, stream>>>(eids, meta, perm);
    scatter_tgt  <<<(E_ + 255) / 256, 256, 0, stream>>>(eids, toff, rank);

    // step schedule: layers [0,0,0, 1, 2,2,2, 3]
    const int layer_of[8] = {0, 0, 0, 1, 2, 2, 2, 3};
    float* target[8] = {bufA, bufB, bufC, bufA, bufB, bufA, bufB, out};

    const float* cur = states;
    const int edge_grid = E_ / EPB + T_;

    for (int s = 0; s < 8; ++s) {
        const int l = layer_of[s];
        edge_gemm<<<edge_grid, 128, 0, stream>>>(
            cur, eids, perm, rank, meta,
            tw + (size_t)l * T_ * H_ * H_, tb + (size_t)l * T_ * H_, msg);
        aggregate<<<BN_ / 2, 256, 0, stream>>>(msg, tstart, agg);

        // A sources: x-part = [res..., agg], then h
        const float* s0; const float* s1; const float* s2; const float* s3;
        int nsrc;
        if (l == 0 || l == 2)      { s0 = agg;    s1 = cur;  s2 = nullptr; s3 = nullptr; nsrc = 1; }
        else if (l == 1)           { s0 = states; s1 = agg;  s2 = cur;     s3 = nullptr; nsrc = 2; }
        else                       { s0 = states; s1 = bufC; s2 = agg;     s3 = cur;     nsrc = 3; }

        dim3 ggrid(BN_ / GM, 8);
        gates_gemm<<<ggrid, 256, 0, stream>>>(s0, s1, s2, s3, gW[l], gU[l], nsrc, gates);

        float* nxt = target[s];
        gru_elem<<<BN_ * H_ / 256, 256, 0, stream>>>(gates, cur, gb[l], nxt);
        cur = nxt;
    }
}

// Round 4
// 1758.783 us; speedup vs baseline: 1.4121x; 1.0017x over previous
//
#include <hip/hip_runtime.h>
#include <math.h>

#define B_  32
#define N_  512
#define H_  128
#define E_  131072
#define T_  9
#define BN_ (B_*N_)
#define EPB 32   // edges per block in edge GEMM

// meta layout (ints): [0..8]=cnt, [9..17]=start, [18..26]=off(atomic), [27..36]=cumBlocks(10)

// ---------------- type sort (LDS-histogram counting sort) ----------------
__global__ void count_types(const int* __restrict__ eids, int* __restrict__ meta) {
    __shared__ int lc[T_];
    if (threadIdx.x < T_) lc[threadIdx.x] = 0;
    __syncthreads();
    int e = blockIdx.x * 256 + threadIdx.x;
    if (e < E_) atomicAdd(&lc[eids[e * 4]], 1);
    __syncthreads();
    if (threadIdx.x < T_ && lc[threadIdx.x]) atomicAdd(&meta[threadIdx.x], lc[threadIdx.x]);
}

__global__ void scan_types(int* meta) {
    int s = 0;
    for (int t = 0; t < T_; ++t) { meta[9 + t] = s; meta[18 + t] = s; s += meta[t]; }
    int cb = 0;
    for (int t = 0; t < T_; ++t) { meta[27 + t] = cb; cb += (meta[t] + EPB - 1) / EPB; }
    meta[27 + T_] = cb;
}

__global__ void scatter_types(const int* __restrict__ eids, int* __restrict__ meta,
                              int* __restrict__ perm) {
    __shared__ int lc[T_], lbase[T_];
    if (threadIdx.x < T_) lc[threadIdx.x] = 0;
    __syncthreads();
    int e = blockIdx.x * 256 + threadIdx.x;
    int t = 0, lp = 0;
    if (e < E_) { t = eids[e * 4]; lp = atomicAdd(&lc[t], 1); }
    __syncthreads();
    if (threadIdx.x < T_ && lc[threadIdx.x])
        lbase[threadIdx.x] = atomicAdd(&meta[18 + threadIdx.x], lc[threadIdx.x]);
    __syncthreads();
    if (e < E_) perm[lbase[t] + lp] = e;
}

// ---------------- target sort (16384 bins; emits rank[e]) ----------------
__global__ void hist_tgt(const int* __restrict__ eids, int* __restrict__ tcnt) {
    int e = blockIdx.x * 256 + threadIdx.x;
    if (e < E_) {
        int tgt = eids[e * 4 + 1] * N_ + eids[e * 4 + 3];
        atomicAdd(&tcnt[tgt], 1);
    }
}

__global__ void scan_tgt(const int* __restrict__ tcnt, int* __restrict__ tstart,
                         int* __restrict__ toff) {
    __shared__ int bs[256];
    const int tid = threadIdx.x;
    const int chunk = BN_ / 256;   // 64
    const int base = tid * chunk;
    int s = 0;
    for (int i = 0; i < chunk; ++i) s += tcnt[base + i];
    bs[tid] = s;
    __syncthreads();
    if (tid == 0) { int acc = 0; for (int i = 0; i < 256; ++i) { int v = bs[i]; bs[i] = acc; acc += v; } }
    __syncthreads();
    int acc = bs[tid];
    for (int i = 0; i < chunk; ++i) {
        int v = tcnt[base + i];
        tstart[base + i] = acc; toff[base + i] = acc; acc += v;
    }
    if (tid == 255) tstart[BN_] = E_;
}

__global__ void scatter_tgt(const int* __restrict__ eids, int* __restrict__ toff,
                            int* __restrict__ rank) {
    int e = blockIdx.x * 256 + threadIdx.x;
    if (e < E_) {
        int tgt = eids[e * 4 + 1] * N_ + eids[e * 4 + 3];
        int pos = atomicAdd(&toff[tgt], 1);
        rank[e] = pos;
    }
}

// ---------------- edge message GEMM (type-sorted; writes in target-rank order) ----------------
__global__ __launch_bounds__(128) void edge_gemm(
    const float* __restrict__ h,
    const int*   __restrict__ eids,
    const int*   __restrict__ perm,
    const int*   __restrict__ rank,
    const int*   __restrict__ meta,
    const float* __restrict__ W,     // (T,H,H) this layer
    const float* __restrict__ bias,  // (T,H)
    float*       __restrict__ msg)   // (E,H) in target-sorted order
{
    __shared__ float src[EPB][H_];
    __shared__ int srcnode[EPB], outrow[EPB];
    __shared__ int info[3];
    const int j = threadIdx.x;

    if (j == 0) {
        int b = blockIdx.x;
        int nb = meta[27 + T_];
        if (b >= nb) info[0] = -1;
        else {
            int t = 0;
            while (b >= meta[27 + t + 1]) t++;
            int chunk = b - meta[27 + t];
            int c = meta[t] - chunk * EPB;
            info[0] = t;
            info[1] = meta[9 + t] + chunk * EPB;
            info[2] = (c > EPB) ? EPB : c;
        }
    }
    __syncthreads();
    const int t = info[0];
    if (t < 0) return;
    const int base = info[1], cnt = info[2];

    if (j < cnt) {
        int e = perm[base + j];
        int eb = eids[e * 4 + 1];
        int es = eids[e * 4 + 2];
        srcnode[j] = eb * N_ + es;
        outrow[j]  = rank[e];
    }
    __syncthreads();
    for (int e = 0; e < cnt; ++e) src[e][j] = h[(size_t)srcnode[e] * H_ + j];
    __syncthreads();

    float acc[EPB];
#pragma unroll
    for (int e = 0; e < EPB; ++e) acc[e] = 0.f;

    const float* Wt = W + (size_t)t * H_ * H_;
    for (int k = 0; k < H_; k += 4) {
        float w0 = Wt[(k + 0) * H_ + j];
        float w1 = Wt[(k + 1) * H_ + j];
        float w2 = Wt[(k + 2) * H_ + j];
        float w3 = Wt[(k + 3) * H_ + j];
#pragma unroll
        for (int e = 0; e < EPB; ++e) {
            float4 s4 = *reinterpret_cast<const float4*>(&src[e][k]);
            acc[e] = fmaf(s4.w, w3, fmaf(s4.z, w2, fmaf(s4.y, w1, fmaf(s4.x, w0, acc[e]))));
        }
    }

    const float bv = bias[t * H_ + j];
    for (int e = 0; e < cnt; ++e)
        msg[(size_t)outrow[e] * H_ + j] = acc[e] + bv;
}

// ---------------- segmented aggregation (contiguous reads, no atomics) ----------------
__global__ __launch_bounds__(256) void aggregate(
    const float* __restrict__ msg,
    const int*   __restrict__ tstart,
    float*       __restrict__ agg)
{
    const int j = threadIdx.x & 127;
    const int n = blockIdx.x * 2 + (threadIdx.x >> 7);
    const int s = tstart[n], e_end = tstart[n + 1];
    float acc = 0.f;
    for (int i = s; i < e_end; ++i) acc += msg[(size_t)i * H_ + j];
    agg[(size_t)n * H_ + j] = acc;
}

// ---------------- GRU gates GEMM: 128x128 tile, 8x8 micro-tile ----------------
// gates (BN,512) = [ z | r | xh | hh ]. panel = blockIdx.y:
//   0: z   cols 0-127,   K = [0, Kx+128)  (W cols 0-127,   U cols 0-127)
//   1: r   cols 128-255, K = [0, Kx+128)  (W cols 128-255, U cols 128-255)
//   2: xh  cols 256-383, K = [0, Kx)      (W cols 256-383)
//   3: hh  cols 384-511, K = [Kx, Kx+128) (U cols 256-383)
#define TM 128
#define TN 128
#define TK 16
__global__ __launch_bounds__(256) void gates_gemm(
    const float* __restrict__ s0, const float* __restrict__ s1,
    const float* __restrict__ s2, const float* __restrict__ s3,
    const float* __restrict__ W,  // (nsrc*128, 384)
    const float* __restrict__ U,  // (128, 384)
    int nsrc,
    float* __restrict__ gates)    // (BN, 512)
{
    __shared__ float As[TK][TM + 4];
    __shared__ float Bs[TK][TN + 4];
    const int tid = threadIdx.x;
    const int m0 = blockIdx.x * TM;
    const int panel = blockIdx.y;
    const int Kx = nsrc * 128;
    const int k_lo = (panel == 3) ? Kx : 0;
    const int k_hi = (panel == 2) ? Kx : Kx + 128;
    const int wcol = (panel == 3) ? 256 : panel * 128;

    const float* srcs[4] = {s0, s1, s2, s3};

    // loader indices
    const int ar = tid >> 2;          // row 0..63 (and +64)
    const int ak = (tid & 3) * 4;     // k-offset 0,4,8,12
    const int bn = (tid & 31) * 4;    // col 0..124
    const int bk = tid >> 5;          // k 0..7 (and +8)

    // compute indices (split mapping: rows {ra,ra+64}, cols {ca,ca+64})
    const int ra = (tid >> 4) * 4;
    const int ca = (tid & 15) * 4;

    float4 a0, a1, b0, b1;
    auto loadA = [&](int k0) {
        const float* sp = srcs[k0 >> 7];
        const int kc = (k0 & 127) + ak;
        a0 = *reinterpret_cast<const float4*>(&sp[(size_t)(m0 + ar) * H_ + kc]);
        a1 = *reinterpret_cast<const float4*>(&sp[(size_t)(m0 + ar + 64) * H_ + kc]);
    };
    auto loadB = [&](int k0) {
        const int ka = k0 + bk, kb = k0 + bk + 8;
        if (panel == 3) {
            b0 = *reinterpret_cast<const float4*>(&U[(size_t)(ka - Kx) * 384 + wcol + bn]);
            b1 = *reinterpret_cast<const float4*>(&U[(size_t)(kb - Kx) * 384 + wcol + bn]);
        } else {
            b0 = (ka < Kx) ? *reinterpret_cast<const float4*>(&W[(size_t)ka * 384 + wcol + bn])
                           : *reinterpret_cast<const float4*>(&U[(size_t)(ka - Kx) * 384 + wcol + bn]);
            b1 = (kb < Kx) ? *reinterpret_cast<const float4*>(&W[(size_t)kb * 384 + wcol + bn])
                           : *reinterpret_cast<const float4*>(&U[(size_t)(kb - Kx) * 384 + wcol + bn]);
        }
    };
    auto storeAB = [&]() {
        As[ak + 0][ar] = a0.x; As[ak + 1][ar] = a0.y; As[ak + 2][ar] = a0.z; As[ak + 3][ar] = a0.w;
        As[ak + 0][ar + 64] = a1.x; As[ak + 1][ar + 64] = a1.y;
        As[ak + 2][ar + 64] = a1.z; As[ak + 3][ar + 64] = a1.w;
        *reinterpret_cast<float4*>(&Bs[bk][bn]) = b0;
        *reinterpret_cast<float4*>(&Bs[bk + 8][bn]) = b1;
    };

    float acc[8][8] = {};
    loadA(k_lo); loadB(k_lo);
    storeAB();
    __syncthreads();

    for (int k0 = k_lo; k0 < k_hi; k0 += TK) {
        const bool more = (k0 + TK < k_hi);
        if (more) { loadA(k0 + TK); loadB(k0 + TK); }
#pragma unroll
        for (int kk = 0; kk < TK; ++kk) {
            float a[8], b[8];
            *reinterpret_cast<float4*>(&a[0]) = *reinterpret_cast<const float4*>(&As[kk][ra]);
            *reinterpret_cast<float4*>(&a[4]) = *reinterpret_cast<const float4*>(&As[kk][ra + 64]);
            *reinterpret_cast<float4*>(&b[0]) = *reinterpret_cast<const float4*>(&Bs[kk][ca]);
            *reinterpret_cast<float4*>(&b[4]) = *reinterpret_cast<const float4*>(&Bs[kk][ca + 64]);
#pragma unroll
            for (int i = 0; i < 8; ++i)
#pragma unroll
                for (int jj = 0; jj < 8; ++jj)
                    acc[i][jj] = fmaf(a[i], b[jj], acc[i][jj]);
        }
        __syncthreads();
        if (more) { storeAB(); }
        __syncthreads();
    }

    const int ncol0 = panel * 128;
#pragma unroll
    for (int i = 0; i < 8; ++i) {
        const int row = m0 + ((i < 4) ? (ra + i) : (ra + 64 + i - 4));
        float* gp = &gates[(size_t)row * 512 + ncol0];
        *reinterpret_cast<float4*>(&gp[ca])      = make_float4(acc[i][0], acc[i][1], acc[i][2], acc[i][3]);
        *reinterpret_cast<float4*>(&gp[ca + 64]) = make_float4(acc[i][4], acc[i][5], acc[i][6], acc[i][7]);
    }
}

// ---------------- GRU elementwise ----------------
__global__ __launch_bounds__(256) void gru_elem(
    const float* __restrict__ gates,
    const float* __restrict__ hcur,
    const float* __restrict__ b,     // (2,384) flat
    float*       __restrict__ hout)
{
    int idx = blockIdx.x * 256 + threadIdx.x;
    int n = idx >> 7, j = idx & 127;
    const float* g = gates + (size_t)n * 512;
    float zpre = g[j]       + b[j]       + b[384 + j];
    float rpre = g[128 + j] + b[128 + j] + b[512 + j];
    float xh   = g[256 + j] + b[256 + j];
    float hh   = g[384 + j] + b[640 + j];
    float z = 1.f / (1.f + expf(-zpre));
    float r = 1.f / (1.f + expf(-rpre));
    float cand = tanhf(xh + r * hh);
    float h = hcur[idx];
    hout[idx] = z * h + (1.f - z) * cand;
}

// ---------------- host orchestration ----------------
extern "C" void kernel_launch(void* const* d_in, const int* in_sizes, int n_in,
                              void* d_out, int out_size, void* d_ws, size_t ws_size,
                              hipStream_t stream) {
    const float* states = (const float*)d_in[0];
    const int*   eids   = (const int*)  d_in[1];
    const float* tw     = (const float*)d_in[2];   // (4,T,H,H)
    const float* tb     = (const float*)d_in[3];   // (4,T,H)
    const float* gW[4]  = { (const float*)d_in[4],  (const float*)d_in[7],
                            (const float*)d_in[10], (const float*)d_in[13] };
    const float* gU[4]  = { (const float*)d_in[5],  (const float*)d_in[8],
                            (const float*)d_in[11], (const float*)d_in[14] };
    const float* gb[4]  = { (const float*)d_in[6],  (const float*)d_in[9],
                            (const float*)d_in[12], (const float*)d_in[15] };
    float* out = (float*)d_out;

    char* ws = (char*)d_ws;
    float* bufA = (float*)ws; ws += (size_t)BN_ * H_ * 4;
    float* bufB = (float*)ws; ws += (size_t)BN_ * H_ * 4;
    float* bufC = (float*)ws; ws += (size_t)BN_ * H_ * 4;   // final layer-0 state
    float* agg  = (float*)ws; ws += (size_t)BN_ * H_ * 4;
    float* msg  = (float*)ws; ws += (size_t)E_ * H_ * 4;    // 64 MB; gates aliases it
    int*   perm  = (int*)ws;  ws += (size_t)E_ * 4;
    int*   rank  = (int*)ws;  ws += (size_t)E_ * 4;
    int*   tcnt  = (int*)ws;  ws += (size_t)BN_ * 4;
    int*   toff  = (int*)ws;  ws += (size_t)BN_ * 4;
    int*   tstart= (int*)ws;  ws += (size_t)(BN_ + 1) * 4;
    int*   meta  = (int*)ws;  ws += 64 * 4;
    float* gates = msg;   // msg dead after aggregate; 33.5MB < 64MB

    // ---- one-time sorts ----
    hipMemsetAsync(meta, 0, 40 * sizeof(int), stream);
    hipMemsetAsync(tcnt, 0, BN_ * sizeof(int), stream);
    count_types<<<(E_ + 255) / 256, 256, 0, stream>>>(eids, meta);
    hist_tgt   <<<(E_ + 255) / 256, 256, 0, stream>>>(eids, tcnt);
    scan_types <<<1, 1, 0, stream>>>(meta);
    scan_tgt   <<<1, 256, 0, stream>>>(tcnt, tstart, toff);
    scatter_types<<<(E_ + 255) / 256, 256, 0, stream>>>(eids, meta, perm);
    scatter_tgt  <<<(E_ + 255) / 256, 256, 0, stream>>>(eids, toff, rank);

    // step schedule: layers [0,0,0, 1, 2,2,2, 3]
    const int layer_of[8] = {0, 0, 0, 1, 2, 2, 2, 3};
    float* target[8] = {bufA, bufB, bufC, bufA, bufB, bufA, bufB, out};

    const float* cur = states;
    const int edge_grid = E_ / EPB + T_;

    for (int s = 0; s < 8; ++s) {
        const int l = layer_of[s];
        edge_gemm<<<edge_grid, 128, 0, stream>>>(
            cur, eids, perm, rank, meta,
            tw + (size_t)l * T_ * H_ * H_, tb + (size_t)l * T_ * H_, msg);
        aggregate<<<BN_ / 2, 256, 0, stream>>>(msg, tstart, agg);

        // A row-sources: x-part = [res..., agg], then h
        const float* s0; const float* s1; const float* s2; const float* s3;
        int nsrc;
        if (l == 0 || l == 2)      { s0 = agg;    s1 = cur;  s2 = nullptr; s3 = nullptr; nsrc = 1; }
        else if (l == 1)           { s0 = states; s1 = agg;  s2 = cur;     s3 = nullptr; nsrc = 2; }
        else                       { s0 = states; s1 = bufC; s2 = agg;     s3 = cur;     nsrc = 3; }

        dim3 ggrid(BN_ / TM, 4);
        gates_gemm<<<ggrid, 256, 0, stream>>>(s0, s1, s2, s3, gW[l], gU[l], nsrc, gates);

        float* nxt = target[s];
        gru_elem<<<BN_ * H_ / 256, 256, 0, stream>>>(gates, cur, gb[l], nxt);
        cur = nxt;
    }
}

// Round 5
// 1356.894 us; speedup vs baseline: 1.8303x; 1.2962x over previous
//
#include <hip/hip_runtime.h>
#include <math.h>

#define B_  32
#define N_  512
#define H_  128
#define E_  131072
#define T_  9
#define BN_ (B_*N_)
#define EPB 32   // edges per block in edge GEMM

typedef unsigned short ushort_t;
typedef __attribute__((ext_vector_type(8))) __bf16 bf16x8;
typedef __attribute__((ext_vector_type(8))) unsigned short ushort8;
typedef __attribute__((ext_vector_type(4))) float f32x4;

// split fp32 -> bf16 hi + bf16 lo (RNE both). v ~= hi + lo with ~2^-17 rel err.
__device__ __forceinline__ void split2(float v, ushort_t &h, ushort_t &l) {
    unsigned u = __builtin_bit_cast(unsigned, v);
    unsigned hb = (u + 0x7FFFu + ((u >> 16) & 1u)) & 0xFFFF0000u;
    h = (ushort_t)(hb >> 16);
    float lv = v - __builtin_bit_cast(float, hb);
    unsigned ul = __builtin_bit_cast(unsigned, lv);
    l = (ushort_t)((ul + 0x7FFFu + ((ul >> 16) & 1u)) >> 16);
}

// meta layout (ints): [0..8]=cnt, [9..17]=start, [18..26]=off(atomic), [27..36]=cumBlocks(10)

// ---------------- type sort (LDS-histogram counting sort) ----------------
__global__ void count_types(const int* __restrict__ eids, int* __restrict__ meta) {
    __shared__ int lc[T_];
    if (threadIdx.x < T_) lc[threadIdx.x] = 0;
    __syncthreads();
    int e = blockIdx.x * 256 + threadIdx.x;
    if (e < E_) atomicAdd(&lc[eids[e * 4]], 1);
    __syncthreads();
    if (threadIdx.x < T_ && lc[threadIdx.x]) atomicAdd(&meta[threadIdx.x], lc[threadIdx.x]);
}

__global__ void scan_types(int* meta) {
    int s = 0;
    for (int t = 0; t < T_; ++t) { meta[9 + t] = s; meta[18 + t] = s; s += meta[t]; }
    int cb = 0;
    for (int t = 0; t < T_; ++t) { meta[27 + t] = cb; cb += (meta[t] + EPB - 1) / EPB; }
    meta[27 + T_] = cb;
}

__global__ void scatter_types(const int* __restrict__ eids, int* __restrict__ meta,
                              int* __restrict__ perm) {
    __shared__ int lc[T_], lbase[T_];
    if (threadIdx.x < T_) lc[threadIdx.x] = 0;
    __syncthreads();
    int e = blockIdx.x * 256 + threadIdx.x;
    int t = 0, lp = 0;
    if (e < E_) { t = eids[e * 4]; lp = atomicAdd(&lc[t], 1); }
    __syncthreads();
    if (threadIdx.x < T_ && lc[threadIdx.x])
        lbase[threadIdx.x] = atomicAdd(&meta[18 + threadIdx.x], lc[threadIdx.x]);
    __syncthreads();
    if (e < E_) perm[lbase[t] + lp] = e;
}

// ---------------- target sort (16384 bins; emits rank[e]) ----------------
__global__ void hist_tgt(const int* __restrict__ eids, int* __restrict__ tcnt) {
    int e = blockIdx.x * 256 + threadIdx.x;
    if (e < E_) {
        int tgt = eids[e * 4 + 1] * N_ + eids[e * 4 + 3];
        atomicAdd(&tcnt[tgt], 1);
    }
}

__global__ void scan_tgt(const int* __restrict__ tcnt, int* __restrict__ tstart,
                         int* __restrict__ toff) {
    __shared__ int bs[256];
    const int tid = threadIdx.x;
    const int chunk = BN_ / 256;   // 64
    const int base = tid * chunk;
    int s = 0;
    for (int i = 0; i < chunk; ++i) s += tcnt[base + i];
    bs[tid] = s;
    __syncthreads();
    if (tid == 0) { int acc = 0; for (int i = 0; i < 256; ++i) { int v = bs[i]; bs[i] = acc; acc += v; } }
    __syncthreads();
    int acc = bs[tid];
    for (int i = 0; i < chunk; ++i) {
        int v = tcnt[base + i];
        tstart[base + i] = acc; toff[base + i] = acc; acc += v;
    }
    if (tid == 255) tstart[BN_] = E_;
}

__global__ void scatter_tgt(const int* __restrict__ eids, int* __restrict__ toff,
                            int* __restrict__ rank) {
    int e = blockIdx.x * 256 + threadIdx.x;
    if (e < E_) {
        int tgt = eids[e * 4 + 1] * N_ + eids[e * 4 + 3];
        int pos = atomicAdd(&toff[tgt], 1);
        rank[e] = pos;
    }
}

// ---------------- edge message GEMM (type-sorted; writes in target-rank order) ----------------
__global__ __launch_bounds__(128) void edge_gemm(
    const float* __restrict__ h,
    const int*   __restrict__ eids,
    const int*   __restrict__ perm,
    const int*   __restrict__ rank,
    const int*   __restrict__ meta,
    const float* __restrict__ W,     // (T,H,H) this layer
    const float* __restrict__ bias,  // (T,H)
    float*       __restrict__ msg)   // (E,H) in target-sorted order
{
    __shared__ float src[EPB][H_];
    __shared__ int srcnode[EPB], outrow[EPB];
    __shared__ int info[3];
    const int j = threadIdx.x;

    if (j == 0) {
        int b = blockIdx.x;
        int nb = meta[27 + T_];
        if (b >= nb) info[0] = -1;
        else {
            int t = 0;
            while (b >= meta[27 + t + 1]) t++;
            int chunk = b - meta[27 + t];
            int c = meta[t] - chunk * EPB;
            info[0] = t;
            info[1] = meta[9 + t] + chunk * EPB;
            info[2] = (c > EPB) ? EPB : c;
        }
    }
    __syncthreads();
    const int t = info[0];
    if (t < 0) return;
    const int base = info[1], cnt = info[2];

    if (j < cnt) {
        int e = perm[base + j];
        int eb = eids[e * 4 + 1];
        int es = eids[e * 4 + 2];
        srcnode[j] = eb * N_ + es;
        outrow[j]  = rank[e];
    }
    __syncthreads();
    for (int e = 0; e < cnt; ++e) src[e][j] = h[(size_t)srcnode[e] * H_ + j];
    __syncthreads();

    float acc[EPB];
#pragma unroll
    for (int e = 0; e < EPB; ++e) acc[e] = 0.f;

    const float* Wt = W + (size_t)t * H_ * H_;
    for (int k = 0; k < H_; k += 4) {
        float w0 = Wt[(k + 0) * H_ + j];
        float w1 = Wt[(k + 1) * H_ + j];
        float w2 = Wt[(k + 2) * H_ + j];
        float w3 = Wt[(k + 3) * H_ + j];
#pragma unroll
        for (int e = 0; e < EPB; ++e) {
            float4 s4 = *reinterpret_cast<const float4*>(&src[e][k]);
            acc[e] = fmaf(s4.w, w3, fmaf(s4.z, w2, fmaf(s4.y, w1, fmaf(s4.x, w0, acc[e]))));
        }
    }

    const float bv = bias[t * H_ + j];
    for (int e = 0; e < cnt; ++e)
        msg[(size_t)outrow[e] * H_ + j] = acc[e] + bv;
}

// ---------------- segmented aggregation (contiguous reads, no atomics) ----------------
__global__ __launch_bounds__(256) void aggregate(
    const float* __restrict__ msg,
    const int*   __restrict__ tstart,
    float*       __restrict__ agg)
{
    const int j = threadIdx.x & 127;
    const int n = blockIdx.x * 2 + (threadIdx.x >> 7);
    const int s = tstart[n], e_end = tstart[n + 1];
    float acc = 0.f;
    for (int i = s; i < e_end; ++i) acc += msg[(size_t)i * H_ + j];
    agg[(size_t)n * H_ + j] = acc;
}

// ---------------- B-hat build: split + transpose weights once per layer ----------------
// BT (512 rows n, K cols k), n = gates column, k over [x (Kx) ; h (128)]:
//   n in [0,256):   W[k][n] (k<Kx) else U[k-Kx][n]          (z, r: summed over full K)
//   n in [256,384): W[k][n] (k<Kx) else 0                    (xh)
//   n in [384,512): U[k-Kx][n-128] (k>=Kx) else 0            (hh)
__global__ void build_bt(const float* __restrict__ W, const float* __restrict__ U,
                         const int Kx, const int K,
                         ushort_t* __restrict__ bth, ushort_t* __restrict__ btl)
{
    int idx = blockIdx.x * 256 + threadIdx.x;
    if (idx >= 512 * K) return;
    int n = idx / K, k = idx - n * K;
    int p = n >> 7;
    float v;
    if (p < 2)       v = (k < Kx) ? W[(size_t)k * 384 + n] : U[(size_t)(k - Kx) * 384 + n];
    else if (p == 2) v = (k < Kx) ? W[(size_t)k * 384 + n] : 0.f;
    else             v = (k >= Kx) ? U[(size_t)(k - Kx) * 384 + (n - 128)] : 0.f;
    split2(v, bth[idx], btl[idx]);
}

// ---------------- gates GEMM via bf16x3 MFMA ----------------
// C (BN,512) = A (BN,K) @ BT^T, A = [sources..., cur] selected per 128-col block.
// 128x128 tile, 4 waves, 4x4 frags of mfma_f32_16x16x32_bf16, 3 MFMA passes
// (ah*bh + al*bh + ah*bl). Double-buffered LDS; B via global_load_lds (pre-split);
// A split in-kernel (issue-early global loads, write-late after compute).
__global__ __launch_bounds__(256) void gates_mfma(
    const float* __restrict__ s0, const float* __restrict__ s1,
    const float* __restrict__ s2, const float* __restrict__ s3,
    const ushort_t* __restrict__ bth, const ushort_t* __restrict__ btl,
    const int K, float* __restrict__ gates)
{
    __shared__ ushort_t Ah[2][128 * 32];
    __shared__ ushort_t Al[2][128 * 32];
    __shared__ ushort_t Bh[2][128 * 32];
    __shared__ ushort_t Bl[2][128 * 32];
    const float* srcs[4] = {s0, s1, s2, s3};
    const int tid = threadIdx.x;
    const int m0 = blockIdx.x * 128;
    const int n0 = blockIdx.y * 128;
    const int w = tid >> 6, l = tid & 63;
    const int wr = (w >> 1) * 64, wc = (w & 1) * 64;
    const int l16 = l & 15, g = l >> 4;

    // A staging: thread owns row ar, logical 8-elem k-blocks {ab, ab+1}
    const int ar  = tid >> 1;
    const int ab  = (tid & 1) * 2;
    const int rho = ar & 3;            // XOR swizzle for LDS-write bank uniformity

    const int bw = w * 32;             // B staging: wave's 32 B-rows

    f32x4 acc[4][4];
#pragma unroll
    for (int i = 0; i < 4; ++i)
#pragma unroll
        for (int j = 0; j < 4; ++j) acc[i][j] = (f32x4){0.f, 0.f, 0.f, 0.f};

    float4 pv[4];
    auto issueA = [&](int k0) {
        const float* sp = srcs[k0 >> 7] + (size_t)(m0 + ar) * H_ + (k0 & 127) + ab * 8;
#pragma unroll
        for (int i = 0; i < 4; ++i) pv[i] = reinterpret_cast<const float4*>(sp)[i];
    };
    auto writeA = [&](int buf) {
        __align__(16) ushort_t hv[16], lv[16];
#pragma unroll
        for (int i = 0; i < 4; ++i) {
            split2(pv[i].x, hv[i * 4 + 0], lv[i * 4 + 0]);
            split2(pv[i].y, hv[i * 4 + 1], lv[i * 4 + 1]);
            split2(pv[i].z, hv[i * 4 + 2], lv[i * 4 + 2]);
            split2(pv[i].w, hv[i * 4 + 3], lv[i * 4 + 3]);
        }
        const int p0 = ((ab + 0) ^ rho) * 8;
        const int p1 = ((ab + 1) ^ rho) * 8;
        *reinterpret_cast<ushort8*>(&Ah[buf][ar * 32 + p0]) = *reinterpret_cast<ushort8*>(&hv[0]);
        *reinterpret_cast<ushort8*>(&Ah[buf][ar * 32 + p1]) = *reinterpret_cast<ushort8*>(&hv[8]);
        *reinterpret_cast<ushort8*>(&Al[buf][ar * 32 + p0]) = *reinterpret_cast<ushort8*>(&lv[0]);
        *reinterpret_cast<ushort8*>(&Al[buf][ar * 32 + p1]) = *reinterpret_cast<ushort8*>(&lv[8]);
    };
    auto stageB = [&](int buf, int k0) {
#pragma unroll
        for (int q = 0; q < 2; ++q) {
            const int row = bw + q * 16 + (l >> 2);
            const size_t off = (size_t)(n0 + row) * K + k0 + (l & 3) * 8;
            __builtin_amdgcn_global_load_lds(
                (const __attribute__((address_space(1))) void*)(bth + off),
                (__attribute__((address_space(3))) void*)&Bh[buf][(bw + q * 16) * 32], 16, 0, 0);
            __builtin_amdgcn_global_load_lds(
                (const __attribute__((address_space(1))) void*)(btl + off),
                (__attribute__((address_space(3))) void*)&Bl[buf][(bw + q * 16) * 32], 16, 0, 0);
        }
    };
    auto compute = [&](int buf) {
        bf16x8 fah[4], fal[4], fbh[4], fbl[4];
#pragma unroll
        for (int f = 0; f < 4; ++f) {
            const int arow = wr + f * 16 + l16;
            const int aoff = arow * 32 + ((g ^ (arow & 3)) * 8);
            fah[f] = *reinterpret_cast<const bf16x8*>(&Ah[buf][aoff]);
            fal[f] = *reinterpret_cast<const bf16x8*>(&Al[buf][aoff]);
            const int boff = (wc + f * 16 + l16) * 32 + g * 8;
            fbh[f] = *reinterpret_cast<const bf16x8*>(&Bh[buf][boff]);
            fbl[f] = *reinterpret_cast<const bf16x8*>(&Bl[buf][boff]);
        }
#pragma unroll
        for (int mf = 0; mf < 4; ++mf)
#pragma unroll
            for (int nf = 0; nf < 4; ++nf)
                acc[mf][nf] = __builtin_amdgcn_mfma_f32_16x16x32_bf16(fah[mf], fbh[nf], acc[mf][nf], 0, 0, 0);
#pragma unroll
        for (int mf = 0; mf < 4; ++mf)
#pragma unroll
            for (int nf = 0; nf < 4; ++nf)
                acc[mf][nf] = __builtin_amdgcn_mfma_f32_16x16x32_bf16(fal[mf], fbh[nf], acc[mf][nf], 0, 0, 0);
#pragma unroll
        for (int mf = 0; mf < 4; ++mf)
#pragma unroll
            for (int nf = 0; nf < 4; ++nf)
                acc[mf][nf] = __builtin_amdgcn_mfma_f32_16x16x32_bf16(fah[mf], fbl[nf], acc[mf][nf], 0, 0, 0);
    };

    // prologue
    issueA(0); writeA(0); stageB(0, 0);
    int cur = 0;
    const int nk = K >> 5;
    for (int ks = 0; ks < nk; ++ks) {
        __syncthreads();                       // staged data (vmcnt+lgkm drained)
        const bool more = (ks + 1 < nk);
        if (more) { issueA((ks + 1) * 32); stageB(cur ^ 1, (ks + 1) * 32); }
        compute(cur);
        if (more) writeA(cur ^ 1);
        cur ^= 1;
    }

    // epilogue: C/D layout col=lane&15, row=(lane>>4)*4+reg
#pragma unroll
    for (int mf = 0; mf < 4; ++mf) {
        const int row = m0 + wr + mf * 16 + g * 4;
#pragma unroll
        for (int nf = 0; nf < 4; ++nf) {
            const int col = n0 + wc + nf * 16 + l16;
#pragma unroll
            for (int r = 0; r < 4; ++r)
                gates[(size_t)(row + r) * 512 + col] = acc[mf][nf][r];
        }
    }
}

// ---------------- GRU elementwise ----------------
__global__ __launch_bounds__(256) void gru_elem(
    const float* __restrict__ gates,
    const float* __restrict__ hcur,
    const float* __restrict__ b,     // (2,384) flat
    float*       __restrict__ hout)
{
    int idx = blockIdx.x * 256 + threadIdx.x;
    int n = idx >> 7, j = idx & 127;
    const float* g = gates + (size_t)n * 512;
    float zpre = g[j]       + b[j]       + b[384 + j];
    float rpre = g[128 + j] + b[128 + j] + b[512 + j];
    float xh   = g[256 + j] + b[256 + j];
    float hh   = g[384 + j] + b[640 + j];
    float z = 1.f / (1.f + expf(-zpre));
    float r = 1.f / (1.f + expf(-rpre));
    float cand = tanhf(xh + r * hh);
    float h = hcur[idx];
    hout[idx] = z * h + (1.f - z) * cand;
}

// ---------------- host orchestration ----------------
extern "C" void kernel_launch(void* const* d_in, const int* in_sizes, int n_in,
                              void* d_out, int out_size, void* d_ws, size_t ws_size,
                              hipStream_t stream) {
    const float* states = (const float*)d_in[0];
    const int*   eids   = (const int*)  d_in[1];
    const float* tw     = (const float*)d_in[2];   // (4,T,H,H)
    const float* tb     = (const float*)d_in[3];   // (4,T,H)
    const float* gW[4]  = { (const float*)d_in[4],  (const float*)d_in[7],
                            (const float*)d_in[10], (const float*)d_in[13] };
    const float* gU[4]  = { (const float*)d_in[5],  (const float*)d_in[8],
                            (const float*)d_in[11], (const float*)d_in[14] };
    const float* gb[4]  = { (const float*)d_in[6],  (const float*)d_in[9],
                            (const float*)d_in[12], (const float*)d_in[15] };
    float* out = (float*)d_out;

    const int KL[4]   = {256, 384, 256, 512};              // IN_DIM + 128 per layer
    const size_t KOFF[4] = {0, 512ull*256, 512ull*(256+384), 512ull*(256+384+256)};
    const size_t BT_TOT  = 512ull * (256 + 384 + 256 + 512);  // 720896 ushorts

    char* ws = (char*)d_ws;
    float* bufA = (float*)ws; ws += (size_t)BN_ * H_ * 4;
    float* bufB = (float*)ws; ws += (size_t)BN_ * H_ * 4;
    float* bufC = (float*)ws; ws += (size_t)BN_ * H_ * 4;   // final layer-0 state
    float* agg  = (float*)ws; ws += (size_t)BN_ * H_ * 4;
    float* msg  = (float*)ws; ws += (size_t)E_ * H_ * 4;    // 64 MB; gates aliases it
    ushort_t* bthAll = (ushort_t*)ws; ws += BT_TOT * 2;     // 16B-aligned (preceded by mult-of-16 sizes)
    ushort_t* btlAll = (ushort_t*)ws; ws += BT_TOT * 2;
    int*   perm  = (int*)ws;  ws += (size_t)E_ * 4;
    int*   rank  = (int*)ws;  ws += (size_t)E_ * 4;
    int*   tcnt  = (int*)ws;  ws += (size_t)BN_ * 4;
    int*   toff  = (int*)ws;  ws += (size_t)BN_ * 4;
    int*   tstart= (int*)ws;  ws += (size_t)(BN_ + 1) * 4;
    int*   meta  = (int*)ws;  ws += 64 * 4;
    float* gates = msg;   // msg dead after aggregate; 33.5MB < 64MB

    // ---- one-time sorts + weight split ----
    hipMemsetAsync(meta, 0, 40 * sizeof(int), stream);
    hipMemsetAsync(tcnt, 0, BN_ * sizeof(int), stream);
    count_types<<<(E_ + 255) / 256, 256, 0, stream>>>(eids, meta);
    hist_tgt   <<<(E_ + 255) / 256, 256, 0, stream>>>(eids, tcnt);
    scan_types <<<1, 1, 0, stream>>>(meta);
    scan_tgt   <<<1, 256, 0, stream>>>(tcnt, tstart, toff);
    scatter_types<<<(E_ + 255) / 256, 256, 0, stream>>>(eids, meta, perm);
    scatter_tgt  <<<(E_ + 255) / 256, 256, 0, stream>>>(eids, toff, rank);
    for (int lyr = 0; lyr < 4; ++lyr) {
        int K = KL[lyr];
        build_bt<<<(512 * K + 255) / 256, 256, 0, stream>>>(
            gW[lyr], gU[lyr], K - 128, K, bthAll + KOFF[lyr], btlAll + KOFF[lyr]);
    }

    // step schedule: layers [0,0,0, 1, 2,2,2, 3]
    const int layer_of[8] = {0, 0, 0, 1, 2, 2, 2, 3};
    float* target[8] = {bufA, bufB, bufC, bufA, bufB, bufA, bufB, out};

    const float* cur = states;
    const int edge_grid = E_ / EPB + T_;

    for (int s = 0; s < 8; ++s) {
        const int l = layer_of[s];
        edge_gemm<<<edge_grid, 128, 0, stream>>>(
            cur, eids, perm, rank, meta,
            tw + (size_t)l * T_ * H_ * H_, tb + (size_t)l * T_ * H_, msg);
        aggregate<<<BN_ / 2, 256, 0, stream>>>(msg, tstart, agg);

        // A sources in order [res..., agg, cur]; K = nsrc*128
        const float* s0; const float* s1; const float* s2; const float* s3;
        if (l == 0 || l == 2)      { s0 = agg;    s1 = cur;  s2 = nullptr; s3 = nullptr; }
        else if (l == 1)           { s0 = states; s1 = agg;  s2 = cur;     s3 = nullptr; }
        else                       { s0 = states; s1 = bufC; s2 = agg;     s3 = cur;     }

        dim3 ggrid(BN_ / 128, 4);
        gates_mfma<<<ggrid, 256, 0, stream>>>(s0, s1, s2, s3,
                                              bthAll + KOFF[l], btlAll + KOFF[l],
                                              KL[l], gates);

        float* nxt = target[s];
        gru_elem<<<BN_ * H_ / 256, 256, 0, stream>>>(gates, cur, gb[l], nxt);
        cur = nxt;
    }
}

// Round 6
// 802.609 us; speedup vs baseline: 3.0944x; 1.6906x over previous
//
#include <hip/hip_runtime.h>
#include <math.h>

#define B_  32
#define N_  512
#define H_  128
#define E_  131072
#define T_  9
#define BN_ (B_*N_)
#define EPB 64   // edges per block in edge MFMA GEMM

typedef unsigned short ushort_t;
typedef __attribute__((ext_vector_type(8))) __bf16 bf16x8;
typedef __attribute__((ext_vector_type(8))) unsigned short ushort8;
typedef __attribute__((ext_vector_type(4))) float f32x4;

// split fp32 -> bf16 hi + bf16 lo (RNE both). v ~= hi + lo with ~2^-17 rel err.
__device__ __forceinline__ void split2(float v, ushort_t &h, ushort_t &l) {
    unsigned u = __builtin_bit_cast(unsigned, v);
    unsigned hb = (u + 0x7FFFu + ((u >> 16) & 1u)) & 0xFFFF0000u;
    h = (ushort_t)(hb >> 16);
    float lv = v - __builtin_bit_cast(float, hb);
    unsigned ul = __builtin_bit_cast(unsigned, lv);
    l = (ushort_t)((ul + 0x7FFFu + ((ul >> 16) & 1u)) >> 16);
}

// meta layout (ints): [0..8]=cnt, [9..17]=start, [18..26]=off(atomic), [27..36]=cumBlocks(10)

// ---------------- type sort (LDS-histogram counting sort) ----------------
__global__ void count_types(const int* __restrict__ eids, int* __restrict__ meta) {
    __shared__ int lc[T_];
    if (threadIdx.x < T_) lc[threadIdx.x] = 0;
    __syncthreads();
    int e = blockIdx.x * 256 + threadIdx.x;
    if (e < E_) atomicAdd(&lc[eids[e * 4]], 1);
    __syncthreads();
    if (threadIdx.x < T_ && lc[threadIdx.x]) atomicAdd(&meta[threadIdx.x], lc[threadIdx.x]);
}

__global__ void scan_types(int* meta) {
    int s = 0;
    for (int t = 0; t < T_; ++t) { meta[9 + t] = s; meta[18 + t] = s; s += meta[t]; }
    int cb = 0;
    for (int t = 0; t < T_; ++t) { meta[27 + t] = cb; cb += (meta[t] + EPB - 1) / EPB; }
    meta[27 + T_] = cb;
}

__global__ void scatter_types(const int* __restrict__ eids, int* __restrict__ meta,
                              int* __restrict__ perm) {
    __shared__ int lc[T_], lbase[T_];
    if (threadIdx.x < T_) lc[threadIdx.x] = 0;
    __syncthreads();
    int e = blockIdx.x * 256 + threadIdx.x;
    int t = 0, lp = 0;
    if (e < E_) { t = eids[e * 4]; lp = atomicAdd(&lc[t], 1); }
    __syncthreads();
    if (threadIdx.x < T_ && lc[threadIdx.x])
        lbase[threadIdx.x] = atomicAdd(&meta[18 + threadIdx.x], lc[threadIdx.x]);
    __syncthreads();
    if (e < E_) perm[lbase[t] + lp] = e;
}

// ---------------- target sort (16384 bins; emits rank[e]) ----------------
__global__ void hist_tgt(const int* __restrict__ eids, int* __restrict__ tcnt) {
    int e = blockIdx.x * 256 + threadIdx.x;
    if (e < E_) {
        int tgt = eids[e * 4 + 1] * N_ + eids[e * 4 + 3];
        atomicAdd(&tcnt[tgt], 1);
    }
}

__global__ void scan_tgt(const int* __restrict__ tcnt, int* __restrict__ tstart,
                         int* __restrict__ toff) {
    __shared__ int bs[256];
    const int tid = threadIdx.x;
    const int chunk = BN_ / 256;   // 64
    const int base = tid * chunk;
    int s = 0;
    for (int i = 0; i < chunk; ++i) s += tcnt[base + i];
    bs[tid] = s;
    __syncthreads();
    if (tid == 0) { int acc = 0; for (int i = 0; i < 256; ++i) { int v = bs[i]; bs[i] = acc; acc += v; } }
    __syncthreads();
    int acc = bs[tid];
    for (int i = 0; i < chunk; ++i) {
        int v = tcnt[base + i];
        tstart[base + i] = acc; toff[base + i] = acc; acc += v;
    }
    if (tid == 255) tstart[BN_] = E_;
}

__global__ void scatter_tgt(const int* __restrict__ eids, int* __restrict__ toff,
                            int* __restrict__ rank) {
    int e = blockIdx.x * 256 + threadIdx.x;
    if (e < E_) {
        int tgt = eids[e * 4 + 1] * N_ + eids[e * 4 + 3];
        int pos = atomicAdd(&toff[tgt], 1);
        rank[e] = pos;
    }
}

// ---------------- weight split/transpose for edge MFMA ----------------
// wt layout in: (T,H,H) = W[t][k][n]; out: wth/wtl (T,128,128) = [t][n][k] bf16 hi/lo
__global__ void build_wt(const float* __restrict__ W,
                         ushort_t* __restrict__ wth, ushort_t* __restrict__ wtl) {
    int idx = blockIdx.x * 256 + threadIdx.x;
    if (idx >= T_ * H_ * H_) return;
    int t = idx / (H_ * H_);
    int rem = idx - t * H_ * H_;
    int n = rem >> 7, k = rem & 127;
    float v = W[(size_t)t * H_ * H_ + k * H_ + n];
    split2(v, wth[idx], wtl[idx]);
}

// ---------------- edge message GEMM via bf16x3 MFMA ----------------
// Block = up to 64 edges of the SAME type. C(64,128) = gathered-src(64,128) @ W[t].
// 4 waves in 2x2: wave covers 32 rows x 64 cols; frags 2(M) x 4(N), K chunks of 32.
__global__ __launch_bounds__(256) void edge_mfma(
    const float* __restrict__ h,
    const int*   __restrict__ eids,
    const int*   __restrict__ perm,
    const int*   __restrict__ rank,
    const int*   __restrict__ meta,
    const ushort_t* __restrict__ wth,  // (T,128,128) [t][n][k]
    const ushort_t* __restrict__ wtl,
    const float* __restrict__ bias,    // (T,H)
    float*       __restrict__ msg)     // (E,H) target-sorted
{
    __shared__ ushort_t Ah[2][EPB * 32], Al[2][EPB * 32];
    __shared__ ushort_t Bh[2][128 * 32], Bl[2][128 * 32];
    __shared__ int srcnode[EPB], outrow[EPB];
    __shared__ int info[3];
    const int tid = threadIdx.x;

    if (tid == 0) {
        int b = blockIdx.x;
        int nb = meta[27 + T_];
        if (b >= nb) info[0] = -1;
        else {
            int t = 0;
            while (b >= meta[27 + t + 1]) t++;
            int chunk = b - meta[27 + t];
            int c = meta[t] - chunk * EPB;
            info[0] = t;
            info[1] = meta[9 + t] + chunk * EPB;
            info[2] = (c > EPB) ? EPB : c;
        }
    }
    __syncthreads();
    const int t = info[0];
    if (t < 0) return;
    const int base = info[1], cnt = info[2];

    if (tid < EPB) {
        int e = perm[base + ((tid < cnt) ? tid : 0)];
        int eb = eids[e * 4 + 1];
        int es = eids[e * 4 + 2];
        srcnode[tid] = eb * N_ + es;
        outrow[tid]  = rank[e];
    }
    __syncthreads();

    const int w = tid >> 6, l = tid & 63;
    const int wr = (w >> 1) * 32, wc = (w & 1) * 64;
    const int l16 = l & 15, g = l >> 4;

    // A staging: thread owns row ar (4 threads/row), k-block kb (8 elems)
    const int ar = tid >> 2;
    const int kb = tid & 3;
    const int bw = w * 32;   // B staging: wave's 32 B-rows (n)

    f32x4 acc[2][4];
#pragma unroll
    for (int i = 0; i < 2; ++i)
#pragma unroll
        for (int j = 0; j < 4; ++j) acc[i][j] = (f32x4){0.f, 0.f, 0.f, 0.f};

    float4 pv[2];
    auto issueA = [&](int k0) {
        const float* sp = h + (size_t)srcnode[ar] * H_ + k0 + kb * 8;
        pv[0] = reinterpret_cast<const float4*>(sp)[0];
        pv[1] = reinterpret_cast<const float4*>(sp)[1];
    };
    auto writeA = [&](int buf) {
        __align__(16) ushort_t hv[8], lv[8];
        split2(pv[0].x, hv[0], lv[0]); split2(pv[0].y, hv[1], lv[1]);
        split2(pv[0].z, hv[2], lv[2]); split2(pv[0].w, hv[3], lv[3]);
        split2(pv[1].x, hv[4], lv[4]); split2(pv[1].y, hv[5], lv[5]);
        split2(pv[1].z, hv[6], lv[6]); split2(pv[1].w, hv[7], lv[7]);
        const int p = (kb ^ (ar & 3)) * 8;
        *reinterpret_cast<ushort8*>(&Ah[buf][ar * 32 + p]) = *reinterpret_cast<ushort8*>(hv);
        *reinterpret_cast<ushort8*>(&Al[buf][ar * 32 + p]) = *reinterpret_cast<ushort8*>(lv);
    };
    auto stageB = [&](int buf, int k0) {
#pragma unroll
        for (int q = 0; q < 2; ++q) {
            const int row = bw + q * 16 + (l >> 2);
            const size_t off = ((size_t)t * 128 + row) * 128 + k0 + (l & 3) * 8;
            __builtin_amdgcn_global_load_lds(
                (const __attribute__((address_space(1))) void*)(wth + off),
                (__attribute__((address_space(3))) void*)&Bh[buf][(bw + q * 16) * 32], 16, 0, 0);
            __builtin_amdgcn_global_load_lds(
                (const __attribute__((address_space(1))) void*)(wtl + off),
                (__attribute__((address_space(3))) void*)&Bl[buf][(bw + q * 16) * 32], 16, 0, 0);
        }
    };
    auto compute = [&](int buf) {
        bf16x8 fah[2], fal[2], fbh[4], fbl[4];
#pragma unroll
        for (int f = 0; f < 2; ++f) {
            const int arow = wr + f * 16 + l16;
            const int aoff = arow * 32 + ((g ^ (arow & 3)) * 8);
            fah[f] = *reinterpret_cast<const bf16x8*>(&Ah[buf][aoff]);
            fal[f] = *reinterpret_cast<const bf16x8*>(&Al[buf][aoff]);
        }
#pragma unroll
        for (int f = 0; f < 4; ++f) {
            const int boff = (wc + f * 16 + l16) * 32 + g * 8;
            fbh[f] = *reinterpret_cast<const bf16x8*>(&Bh[buf][boff]);
            fbl[f] = *reinterpret_cast<const bf16x8*>(&Bl[buf][boff]);
        }
#pragma unroll
        for (int mf = 0; mf < 2; ++mf)
#pragma unroll
            for (int nf = 0; nf < 4; ++nf)
                acc[mf][nf] = __builtin_amdgcn_mfma_f32_16x16x32_bf16(fah[mf], fbh[nf], acc[mf][nf], 0, 0, 0);
#pragma unroll
        for (int mf = 0; mf < 2; ++mf)
#pragma unroll
            for (int nf = 0; nf < 4; ++nf)
                acc[mf][nf] = __builtin_amdgcn_mfma_f32_16x16x32_bf16(fal[mf], fbh[nf], acc[mf][nf], 0, 0, 0);
#pragma unroll
        for (int mf = 0; mf < 2; ++mf)
#pragma unroll
            for (int nf = 0; nf < 4; ++nf)
                acc[mf][nf] = __builtin_amdgcn_mfma_f32_16x16x32_bf16(fah[mf], fbl[nf], acc[mf][nf], 0, 0, 0);
    };

    issueA(0); writeA(0); stageB(0, 0);
    int cur = 0;
    for (int ks = 0; ks < 4; ++ks) {
        __syncthreads();
        const bool more = (ks + 1 < 4);
        if (more) { issueA((ks + 1) * 32); stageB(cur ^ 1, (ks + 1) * 32); }
        compute(cur);
        if (more) writeA(cur ^ 1);
        cur ^= 1;
    }

    // epilogue: C/D layout col=lane&15, row=(lane>>4)*4+reg
#pragma unroll
    for (int mf = 0; mf < 2; ++mf) {
        const int rbase = wr + mf * 16 + g * 4;
#pragma unroll
        for (int nf = 0; nf < 4; ++nf) {
            const int col = wc + nf * 16 + l16;
            const float bv = bias[t * H_ + col];
#pragma unroll
            for (int r = 0; r < 4; ++r) {
                const int row = rbase + r;
                if (row < cnt)
                    msg[(size_t)outrow[row] * H_ + col] = acc[mf][nf][r] + bv;
            }
        }
    }
}

// ---------------- segmented aggregation (contiguous reads, no atomics) ----------------
__global__ __launch_bounds__(256) void aggregate(
    const float* __restrict__ msg,
    const int*   __restrict__ tstart,
    float*       __restrict__ agg)
{
    const int j = threadIdx.x & 127;
    const int n = blockIdx.x * 2 + (threadIdx.x >> 7);
    const int s = tstart[n], e_end = tstart[n + 1];
    float acc = 0.f;
    for (int i = s; i < e_end; ++i) acc += msg[(size_t)i * H_ + j];
    agg[(size_t)n * H_ + j] = acc;
}

// ---------------- B-hat build: split + transpose GRU weights once per layer ----------------
__global__ void build_bt(const float* __restrict__ W, const float* __restrict__ U,
                         const int Kx, const int K,
                         ushort_t* __restrict__ bth, ushort_t* __restrict__ btl)
{
    int idx = blockIdx.x * 256 + threadIdx.x;
    if (idx >= 512 * K) return;
    int n = idx / K, k = idx - n * K;
    int p = n >> 7;
    float v;
    if (p < 2)       v = (k < Kx) ? W[(size_t)k * 384 + n] : U[(size_t)(k - Kx) * 384 + n];
    else if (p == 2) v = (k < Kx) ? W[(size_t)k * 384 + n] : 0.f;
    else             v = (k >= Kx) ? U[(size_t)(k - Kx) * 384 + (n - 128)] : 0.f;
    split2(v, bth[idx], btl[idx]);
}

// ---------------- gates GEMM via bf16x3 MFMA ----------------
__global__ __launch_bounds__(256) void gates_mfma(
    const float* __restrict__ s0, const float* __restrict__ s1,
    const float* __restrict__ s2, const float* __restrict__ s3,
    const ushort_t* __restrict__ bth, const ushort_t* __restrict__ btl,
    const int K, float* __restrict__ gates)
{
    __shared__ ushort_t Ah[2][128 * 32];
    __shared__ ushort_t Al[2][128 * 32];
    __shared__ ushort_t Bh[2][128 * 32];
    __shared__ ushort_t Bl[2][128 * 32];
    const float* srcs[4] = {s0, s1, s2, s3};
    const int tid = threadIdx.x;
    const int m0 = blockIdx.x * 128;
    const int n0 = blockIdx.y * 128;
    const int w = tid >> 6, l = tid & 63;
    const int wr = (w >> 1) * 64, wc = (w & 1) * 64;
    const int l16 = l & 15, g = l >> 4;

    const int ar  = tid >> 1;
    const int ab  = (tid & 1) * 2;
    const int rho = ar & 3;

    const int bw = w * 32;

    f32x4 acc[4][4];
#pragma unroll
    for (int i = 0; i < 4; ++i)
#pragma unroll
        for (int j = 0; j < 4; ++j) acc[i][j] = (f32x4){0.f, 0.f, 0.f, 0.f};

    float4 pv[4];
    auto issueA = [&](int k0) {
        const float* sp = srcs[k0 >> 7] + (size_t)(m0 + ar) * H_ + (k0 & 127) + ab * 8;
#pragma unroll
        for (int i = 0; i < 4; ++i) pv[i] = reinterpret_cast<const float4*>(sp)[i];
    };
    auto writeA = [&](int buf) {
        __align__(16) ushort_t hv[16], lv[16];
#pragma unroll
        for (int i = 0; i < 4; ++i) {
            split2(pv[i].x, hv[i * 4 + 0], lv[i * 4 + 0]);
            split2(pv[i].y, hv[i * 4 + 1], lv[i * 4 + 1]);
            split2(pv[i].z, hv[i * 4 + 2], lv[i * 4 + 2]);
            split2(pv[i].w, hv[i * 4 + 3], lv[i * 4 + 3]);
        }
        const int p0 = ((ab + 0) ^ rho) * 8;
        const int p1 = ((ab + 1) ^ rho) * 8;
        *reinterpret_cast<ushort8*>(&Ah[buf][ar * 32 + p0]) = *reinterpret_cast<ushort8*>(&hv[0]);
        *reinterpret_cast<ushort8*>(&Ah[buf][ar * 32 + p1]) = *reinterpret_cast<ushort8*>(&hv[8]);
        *reinterpret_cast<ushort8*>(&Al[buf][ar * 32 + p0]) = *reinterpret_cast<ushort8*>(&lv[0]);
        *reinterpret_cast<ushort8*>(&Al[buf][ar * 32 + p1]) = *reinterpret_cast<ushort8*>(&lv[8]);
    };
    auto stageB = [&](int buf, int k0) {
#pragma unroll
        for (int q = 0; q < 2; ++q) {
            const int row = bw + q * 16 + (l >> 2);
            const size_t off = (size_t)(n0 + row) * K + k0 + (l & 3) * 8;
            __builtin_amdgcn_global_load_lds(
                (const __attribute__((address_space(1))) void*)(bth + off),
                (__attribute__((address_space(3))) void*)&Bh[buf][(bw + q * 16) * 32], 16, 0, 0);
            __builtin_amdgcn_global_load_lds(
                (const __attribute__((address_space(1))) void*)(btl + off),
                (__attribute__((address_space(3))) void*)&Bl[buf][(bw + q * 16) * 32], 16, 0, 0);
        }
    };
    auto compute = [&](int buf) {
        bf16x8 fah[4], fal[4], fbh[4], fbl[4];
#pragma unroll
        for (int f = 0; f < 4; ++f) {
            const int arow = wr + f * 16 + l16;
            const int aoff = arow * 32 + ((g ^ (arow & 3)) * 8);
            fah[f] = *reinterpret_cast<const bf16x8*>(&Ah[buf][aoff]);
            fal[f] = *reinterpret_cast<const bf16x8*>(&Al[buf][aoff]);
            const int boff = (wc + f * 16 + l16) * 32 + g * 8;
            fbh[f] = *reinterpret_cast<const bf16x8*>(&Bh[buf][boff]);
            fbl[f] = *reinterpret_cast<const bf16x8*>(&Bl[buf][boff]);
        }
#pragma unroll
        for (int mf = 0; mf < 4; ++mf)
#pragma unroll
            for (int nf = 0; nf < 4; ++nf)
                acc[mf][nf] = __builtin_amdgcn_mfma_f32_16x16x32_bf16(fah[mf], fbh[nf], acc[mf][nf], 0, 0, 0);
#pragma unroll
        for (int mf = 0; mf < 4; ++mf)
#pragma unroll
            for (int nf = 0; nf < 4; ++nf)
                acc[mf][nf] = __builtin_amdgcn_mfma_f32_16x16x32_bf16(fal[mf], fbh[nf], acc[mf][nf], 0, 0, 0);
#pragma unroll
        for (int mf = 0; mf < 4; ++mf)
#pragma unroll
            for (int nf = 0; nf < 4; ++nf)
                acc[mf][nf] = __builtin_amdgcn_mfma_f32_16x16x32_bf16(fah[mf], fbl[nf], acc[mf][nf], 0, 0, 0);
    };

    issueA(0); writeA(0); stageB(0, 0);
    int cur = 0;
    const int nk = K >> 5;
    for (int ks = 0; ks < nk; ++ks) {
        __syncthreads();
        const bool more = (ks + 1 < nk);
        if (more) { issueA((ks + 1) * 32); stageB(cur ^ 1, (ks + 1) * 32); }
        compute(cur);
        if (more) writeA(cur ^ 1);
        cur ^= 1;
    }

#pragma unroll
    for (int mf = 0; mf < 4; ++mf) {
        const int row = m0 + wr + mf * 16 + g * 4;
#pragma unroll
        for (int nf = 0; nf < 4; ++nf) {
            const int col = n0 + wc + nf * 16 + l16;
#pragma unroll
            for (int r = 0; r < 4; ++r)
                gates[(size_t)(row + r) * 512 + col] = acc[mf][nf][r];
        }
    }
}

// ---------------- GRU elementwise ----------------
__global__ __launch_bounds__(256) void gru_elem(
    const float* __restrict__ gates,
    const float* __restrict__ hcur,
    const float* __restrict__ b,     // (2,384) flat
    float*       __restrict__ hout)
{
    int idx = blockIdx.x * 256 + threadIdx.x;
    int n = idx >> 7, j = idx & 127;
    const float* g = gates + (size_t)n * 512;
    float zpre = g[j]       + b[j]       + b[384 + j];
    float rpre = g[128 + j] + b[128 + j] + b[512 + j];
    float xh   = g[256 + j] + b[256 + j];
    float hh   = g[384 + j] + b[640 + j];
    float z = 1.f / (1.f + expf(-zpre));
    float r = 1.f / (1.f + expf(-rpre));
    float cand = tanhf(xh + r * hh);
    float h = hcur[idx];
    hout[idx] = z * h + (1.f - z) * cand;
}

// ---------------- host orchestration ----------------
extern "C" void kernel_launch(void* const* d_in, const int* in_sizes, int n_in,
                              void* d_out, int out_size, void* d_ws, size_t ws_size,
                              hipStream_t stream) {
    const float* states = (const float*)d_in[0];
    const int*   eids   = (const int*)  d_in[1];
    const float* tw     = (const float*)d_in[2];   // (4,T,H,H)
    const float* tb     = (const float*)d_in[3];   // (4,T,H)
    const float* gW[4]  = { (const float*)d_in[4],  (const float*)d_in[7],
                            (const float*)d_in[10], (const float*)d_in[13] };
    const float* gU[4]  = { (const float*)d_in[5],  (const float*)d_in[8],
                            (const float*)d_in[11], (const float*)d_in[14] };
    const float* gb[4]  = { (const float*)d_in[6],  (const float*)d_in[9],
                            (const float*)d_in[12], (const float*)d_in[15] };
    float* out = (float*)d_out;

    const int KL[4]   = {256, 384, 256, 512};              // IN_DIM + 128 per layer
    const size_t KOFF[4] = {0, 512ull*256, 512ull*(256+384), 512ull*(256+384+256)};
    const size_t BT_TOT  = 512ull * (256 + 384 + 256 + 512);   // 720896 ushorts
    const size_t WT_L    = (size_t)T_ * H_ * H_;               // per-layer W plane

    char* ws = (char*)d_ws;
    float* bufA = (float*)ws; ws += (size_t)BN_ * H_ * 4;
    float* bufB = (float*)ws; ws += (size_t)BN_ * H_ * 4;
    float* bufC = (float*)ws; ws += (size_t)BN_ * H_ * 4;   // final layer-0 state
    float* agg  = (float*)ws; ws += (size_t)BN_ * H_ * 4;
    float* msg  = (float*)ws; ws += (size_t)E_ * H_ * 4;    // 64 MB; gates aliases it
    ushort_t* bthAll = (ushort_t*)ws; ws += BT_TOT * 2;
    ushort_t* btlAll = (ushort_t*)ws; ws += BT_TOT * 2;
    ushort_t* wthAll = (ushort_t*)ws; ws += 4 * WT_L * 2;   // (4,T,128,128) hi
    ushort_t* wtlAll = (ushort_t*)ws; ws += 4 * WT_L * 2;   // lo
    int*   perm  = (int*)ws;  ws += (size_t)E_ * 4;
    int*   rank  = (int*)ws;  ws += (size_t)E_ * 4;
    int*   tcnt  = (int*)ws;  ws += (size_t)BN_ * 4;
    int*   toff  = (int*)ws;  ws += (size_t)BN_ * 4;
    int*   tstart= (int*)ws;  ws += (size_t)(BN_ + 1) * 4;
    int*   meta  = (int*)ws;  ws += 64 * 4;
    float* gates = msg;   // msg dead after aggregate; 33.5MB < 64MB

    // ---- one-time sorts + weight splits ----
    hipMemsetAsync(meta, 0, 40 * sizeof(int), stream);
    hipMemsetAsync(tcnt, 0, BN_ * sizeof(int), stream);
    count_types<<<(E_ + 255) / 256, 256, 0, stream>>>(eids, meta);
    hist_tgt   <<<(E_ + 255) / 256, 256, 0, stream>>>(eids, tcnt);
    scan_types <<<1, 1, 0, stream>>>(meta);
    scan_tgt   <<<1, 256, 0, stream>>>(tcnt, tstart, toff);
    scatter_types<<<(E_ + 255) / 256, 256, 0, stream>>>(eids, meta, perm);
    scatter_tgt  <<<(E_ + 255) / 256, 256, 0, stream>>>(eids, toff, rank);
    for (int lyr = 0; lyr < 4; ++lyr) {
        int K = KL[lyr];
        build_bt<<<(512 * K + 255) / 256, 256, 0, stream>>>(
            gW[lyr], gU[lyr], K - 128, K, bthAll + KOFF[lyr], btlAll + KOFF[lyr]);
        build_wt<<<((int)WT_L + 255) / 256, 256, 0, stream>>>(
            tw + lyr * WT_L, wthAll + lyr * WT_L, wtlAll + lyr * WT_L);
    }

    // step schedule: layers [0,0,0, 1, 2,2,2, 3]
    const int layer_of[8] = {0, 0, 0, 1, 2, 2, 2, 3};
    float* target[8] = {bufA, bufB, bufC, bufA, bufB, bufA, bufB, out};

    const float* cur = states;
    const int edge_grid = E_ / EPB + T_;

    for (int s = 0; s < 8; ++s) {
        const int l = layer_of[s];
        edge_mfma<<<edge_grid, 256, 0, stream>>>(
            cur, eids, perm, rank, meta,
            wthAll + l * WT_L, wtlAll + l * WT_L, tb + (size_t)l * T_ * H_, msg);
        aggregate<<<BN_ / 2, 256, 0, stream>>>(msg, tstart, agg);

        const float* s0; const float* s1; const float* s2; const float* s3;
        if (l == 0 || l == 2)      { s0 = agg;    s1 = cur;  s2 = nullptr; s3 = nullptr; }
        else if (l == 1)           { s0 = states; s1 = agg;  s2 = cur;     s3 = nullptr; }
        else                       { s0 = states; s1 = bufC; s2 = agg;     s3 = cur;     }

        dim3 ggrid(BN_ / 128, 4);
        gates_mfma<<<ggrid, 256, 0, stream>>>(s0, s1, s2, s3,
                                              bthAll + KOFF[l], btlAll + KOFF[l],
                                              KL[l], gates);

        float* nxt = target[s];
        gru_elem<<<BN_ * H_ / 256, 256, 0, stream>>>(gates, cur, gb[l], nxt);
        cur = nxt;
    }
}

// Round 7
// 785.125 us; speedup vs baseline: 3.1633x; 1.0223x over previous
//
#include <hip/hip_runtime.h>
#include <math.h>

#define B_  32
#define N_  512
#define H_  128
#define E_  131072
#define T_  9
#define BN_ (B_*N_)
#define EPB 64   // edges per block in edge MFMA GEMM
#define FM  32   // rows per block in fused GRU kernel

typedef unsigned short ushort_t;
typedef __attribute__((ext_vector_type(8))) __bf16 bf16x8;
typedef __attribute__((ext_vector_type(8))) unsigned short ushort8;
typedef __attribute__((ext_vector_type(4))) float f32x4;

// split fp32 -> bf16 hi + bf16 lo (RNE both). v ~= hi + lo with ~2^-17 rel err.
__device__ __forceinline__ void split2(float v, ushort_t &h, ushort_t &l) {
    unsigned u = __builtin_bit_cast(unsigned, v);
    unsigned hb = (u + 0x7FFFu + ((u >> 16) & 1u)) & 0xFFFF0000u;
    h = (ushort_t)(hb >> 16);
    float lv = v - __builtin_bit_cast(float, hb);
    unsigned ul = __builtin_bit_cast(unsigned, lv);
    l = (ushort_t)((ul + 0x7FFFu + ((ul >> 16) & 1u)) >> 16);
}

// k-slot swizzle baked into global weight layout (G21: gload_lds dest linear,
// read applies same XOR). slot(k,n) = ((k>>3)&3) ^ ((n>>1)&3) -> 2-way banks.
__device__ __forceinline__ int kswz(int k, int n) {
    return (k & ~31) | (((((k >> 3) & 3) ^ ((n >> 1) & 3))) << 3) | (k & 7);
}

// meta layout (ints): [0..8]=cnt, [9..17]=start, [18..26]=off(atomic), [27..36]=cumBlocks(10)

// ---------------- fused histograms (type + target) ----------------
__global__ void count_all(const int* __restrict__ eids, int* __restrict__ meta,
                          int* __restrict__ tcnt) {
    __shared__ int lc[T_];
    if (threadIdx.x < T_) lc[threadIdx.x] = 0;
    __syncthreads();
    int e = blockIdx.x * 256 + threadIdx.x;
    if (e < E_) {
        int4 v = reinterpret_cast<const int4*>(eids)[e];
        atomicAdd(&lc[v.x], 1);
        atomicAdd(&tcnt[v.y * N_ + v.w], 1);
    }
    __syncthreads();
    if (threadIdx.x < T_ && lc[threadIdx.x]) atomicAdd(&meta[threadIdx.x], lc[threadIdx.x]);
}

__global__ void scan_types(int* meta) {
    int s = 0;
    for (int t = 0; t < T_; ++t) { meta[9 + t] = s; meta[18 + t] = s; s += meta[t]; }
    int cb = 0;
    for (int t = 0; t < T_; ++t) { meta[27 + t] = cb; cb += (meta[t] + EPB - 1) / EPB; }
    meta[27 + T_] = cb;
}

__global__ void scan_tgt(const int* __restrict__ tcnt, int* __restrict__ tstart,
                         int* __restrict__ toff) {
    __shared__ int bs[256];
    const int tid = threadIdx.x;
    const int chunk = BN_ / 256;   // 64
    const int base = tid * chunk;
    int s = 0;
    for (int i = 0; i < chunk; ++i) s += tcnt[base + i];
    bs[tid] = s;
    __syncthreads();
    if (tid == 0) { int acc = 0; for (int i = 0; i < 256; ++i) { int v = bs[i]; bs[i] = acc; acc += v; } }
    __syncthreads();
    int acc = bs[tid];
    for (int i = 0; i < chunk; ++i) {
        int v = tcnt[base + i];
        tstart[base + i] = acc; toff[base + i] = acc; acc += v;
    }
    if (tid == 255) tstart[BN_] = E_;
}

// ---------------- fused scatter (type perm + target rank) ----------------
__global__ void scatter_all(const int* __restrict__ eids, int* __restrict__ meta,
                            int* __restrict__ toff, int* __restrict__ perm,
                            int* __restrict__ rank) {
    __shared__ int lc[T_], lbase[T_];
    if (threadIdx.x < T_) lc[threadIdx.x] = 0;
    __syncthreads();
    int e = blockIdx.x * 256 + threadIdx.x;
    int4 v = {0, 0, 0, 0};
    int lp = 0;
    if (e < E_) { v = reinterpret_cast<const int4*>(eids)[e]; lp = atomicAdd(&lc[v.x], 1); }
    __syncthreads();
    if (threadIdx.x < T_ && lc[threadIdx.x])
        lbase[threadIdx.x] = atomicAdd(&meta[18 + threadIdx.x], lc[threadIdx.x]);
    __syncthreads();
    if (e < E_) {
        perm[lbase[v.x] + lp] = e;
        rank[e] = atomicAdd(&toff[v.y * N_ + v.w], 1);
    }
}

// ---------------- weight split/transpose for edge MFMA ----------------
// in: (T,H,H) = W[t][k][n]; out: (T,128,128) = [t][n][kswz(k,n)] bf16 hi/lo
__global__ void build_wt(const float* __restrict__ W,
                         ushort_t* __restrict__ wth, ushort_t* __restrict__ wtl) {
    int idx = blockIdx.x * 256 + threadIdx.x;
    if (idx >= T_ * H_ * H_) return;
    int t = idx / (H_ * H_);
    int rem = idx - t * H_ * H_;
    int n = rem >> 7, k = rem & 127;
    float v = W[(size_t)t * H_ * H_ + k * H_ + n];
    size_t o = (size_t)t * H_ * H_ + n * 128 + kswz(k, n);
    split2(v, wth[o], wtl[o]);
}

// ---------------- edge message GEMM via bf16x3 MFMA ----------------
__global__ __launch_bounds__(256) void edge_mfma(
    const float* __restrict__ h,
    const int*   __restrict__ eids,
    const int*   __restrict__ perm,
    const int*   __restrict__ rank,
    const int*   __restrict__ meta,
    const ushort_t* __restrict__ wth,  // (T,128,128) [t][n][k swz]
    const ushort_t* __restrict__ wtl,
    const float* __restrict__ bias,    // (T,H)
    float*       __restrict__ msg)     // (E,H) target-sorted
{
    __shared__ ushort_t Ah[2][EPB * 32], Al[2][EPB * 32];
    __shared__ ushort_t Bh[2][128 * 32], Bl[2][128 * 32];
    __shared__ int srcnode[EPB], outrow[EPB];
    __shared__ int info[3];
    const int tid = threadIdx.x;

    if (tid == 0) {
        int b = blockIdx.x;
        int nb = meta[27 + T_];
        if (b >= nb) info[0] = -1;
        else {
            int t = 0;
            while (b >= meta[27 + t + 1]) t++;
            int chunk = b - meta[27 + t];
            int c = meta[t] - chunk * EPB;
            info[0] = t;
            info[1] = meta[9 + t] + chunk * EPB;
            info[2] = (c > EPB) ? EPB : c;
        }
    }
    __syncthreads();
    const int t = info[0];
    if (t < 0) return;
    const int base = info[1], cnt = info[2];

    if (tid < EPB) {
        int e = perm[base + ((tid < cnt) ? tid : 0)];
        int eb = eids[e * 4 + 1];
        int es = eids[e * 4 + 2];
        srcnode[tid] = eb * N_ + es;
        outrow[tid]  = rank[e];
    }
    __syncthreads();

    const int w = tid >> 6, l = tid & 63;
    const int wr = (w >> 1) * 32, wc = (w & 1) * 64;
    const int l16 = l & 15, g = l >> 4;

    const int ar = tid >> 2;          // A row (4 threads/row)
    const int kb = tid & 3;           // 8-elem k block
    const int bw = w * 32;            // B staging: wave's 32 B-rows

    f32x4 acc[2][4];
#pragma unroll
    for (int i = 0; i < 2; ++i)
#pragma unroll
        for (int j = 0; j < 4; ++j) acc[i][j] = (f32x4){0.f, 0.f, 0.f, 0.f};

    float4 pv[2];
    auto issueA = [&](int k0) {
        const float* sp = h + (size_t)srcnode[ar] * H_ + k0 + kb * 8;
        pv[0] = reinterpret_cast<const float4*>(sp)[0];
        pv[1] = reinterpret_cast<const float4*>(sp)[1];
    };
    auto writeA = [&](int buf) {
        __align__(16) ushort_t hv[8], lv[8];
        split2(pv[0].x, hv[0], lv[0]); split2(pv[0].y, hv[1], lv[1]);
        split2(pv[0].z, hv[2], lv[2]); split2(pv[0].w, hv[3], lv[3]);
        split2(pv[1].x, hv[4], lv[4]); split2(pv[1].y, hv[5], lv[5]);
        split2(pv[1].z, hv[6], lv[6]); split2(pv[1].w, hv[7], lv[7]);
        const int p = (kb ^ ((ar >> 1) & 3)) * 8;
        *reinterpret_cast<ushort8*>(&Ah[buf][ar * 32 + p]) = *reinterpret_cast<ushort8*>(hv);
        *reinterpret_cast<ushort8*>(&Al[buf][ar * 32 + p]) = *reinterpret_cast<ushort8*>(lv);
    };
    auto stageB = [&](int buf, int k0) {
#pragma unroll
        for (int q = 0; q < 2; ++q) {
            const int row = bw + q * 16 + (l >> 2);
            const size_t off = ((size_t)t * 128 + row) * 128 + k0 + (l & 3) * 8;
            __builtin_amdgcn_global_load_lds(
                (const __attribute__((address_space(1))) void*)(wth + off),
                (__attribute__((address_space(3))) void*)&Bh[buf][(bw + q * 16) * 32], 16, 0, 0);
            __builtin_amdgcn_global_load_lds(
                (const __attribute__((address_space(1))) void*)(wtl + off),
                (__attribute__((address_space(3))) void*)&Bl[buf][(bw + q * 16) * 32], 16, 0, 0);
        }
    };
    auto compute = [&](int buf) {
        bf16x8 fah[2], fal[2], fbh[4], fbl[4];
#pragma unroll
        for (int f = 0; f < 2; ++f) {
            const int arow = wr + f * 16 + l16;
            const int aoff = arow * 32 + ((g ^ ((arow >> 1) & 3)) * 8);
            fah[f] = *reinterpret_cast<const bf16x8*>(&Ah[buf][aoff]);
            fal[f] = *reinterpret_cast<const bf16x8*>(&Al[buf][aoff]);
        }
#pragma unroll
        for (int f = 0; f < 4; ++f) {
            const int brow = wc + f * 16 + l16;
            const int boff = brow * 32 + ((g ^ ((brow >> 1) & 3)) * 8);
            fbh[f] = *reinterpret_cast<const bf16x8*>(&Bh[buf][boff]);
            fbl[f] = *reinterpret_cast<const bf16x8*>(&Bl[buf][boff]);
        }
#pragma unroll
        for (int mf = 0; mf < 2; ++mf)
#pragma unroll
            for (int nf = 0; nf < 4; ++nf)
                acc[mf][nf] = __builtin_amdgcn_mfma_f32_16x16x32_bf16(fah[mf], fbh[nf], acc[mf][nf], 0, 0, 0);
#pragma unroll
        for (int mf = 0; mf < 2; ++mf)
#pragma unroll
            for (int nf = 0; nf < 4; ++nf)
                acc[mf][nf] = __builtin_amdgcn_mfma_f32_16x16x32_bf16(fal[mf], fbh[nf], acc[mf][nf], 0, 0, 0);
#pragma unroll
        for (int mf = 0; mf < 2; ++mf)
#pragma unroll
            for (int nf = 0; nf < 4; ++nf)
                acc[mf][nf] = __builtin_amdgcn_mfma_f32_16x16x32_bf16(fah[mf], fbl[nf], acc[mf][nf], 0, 0, 0);
    };

    issueA(0); writeA(0); stageB(0, 0);
    int cur = 0;
    for (int ks = 0; ks < 4; ++ks) {
        __syncthreads();
        const bool more = (ks + 1 < 4);
        if (more) { issueA((ks + 1) * 32); stageB(cur ^ 1, (ks + 1) * 32); }
        compute(cur);
        if (more) writeA(cur ^ 1);
        cur ^= 1;
    }

    // epilogue: C/D layout col=lane&15, row=(lane>>4)*4+reg
#pragma unroll
    for (int mf = 0; mf < 2; ++mf) {
        const int rbase = wr + mf * 16 + g * 4;
#pragma unroll
        for (int nf = 0; nf < 4; ++nf) {
            const int col = wc + nf * 16 + l16;
            const float bv = bias[t * H_ + col];
#pragma unroll
            for (int r = 0; r < 4; ++r) {
                const int row = rbase + r;
                if (row < cnt)
                    msg[(size_t)outrow[row] * H_ + col] = acc[mf][nf][r] + bv;
            }
        }
    }
}

// ---------------- segmented aggregation (contiguous reads, no atomics) ----------------
__global__ __launch_bounds__(256) void aggregate(
    const float* __restrict__ msg,
    const int*   __restrict__ tstart,
    float*       __restrict__ agg)
{
    const int j = threadIdx.x & 127;
    const int n = blockIdx.x * 2 + (threadIdx.x >> 7);
    const int s = tstart[n], e_end = tstart[n + 1];
    float acc = 0.f;
    for (int i = s; i < e_end; ++i) acc += msg[(size_t)i * H_ + j];
    agg[(size_t)n * H_ + j] = acc;
}

// ---------------- B-hat build: split + transpose GRU weights (k-swizzled) ----------------
__global__ void build_bt(const float* __restrict__ W, const float* __restrict__ U,
                         const int Kx, const int K,
                         ushort_t* __restrict__ bth, ushort_t* __restrict__ btl)
{
    int idx = blockIdx.x * 256 + threadIdx.x;
    if (idx >= 512 * K) return;
    int n = idx / K, k = idx - n * K;
    int p = n >> 7;
    float v;
    if (p < 2)       v = (k < Kx) ? W[(size_t)k * 384 + n] : U[(size_t)(k - Kx) * 384 + n];
    else if (p == 2) v = (k < Kx) ? W[(size_t)k * 384 + n] : 0.f;
    else             v = (k >= Kx) ? U[(size_t)(k - Kx) * 384 + (n - 128)] : 0.f;
    size_t o = (size_t)n * K + kswz(k, n);
    split2(v, bth[o], btl[o]);
}

// ---------------- fused GRU: 4-panel bf16x3 MFMA GEMM + in-register gate math ----------------
// Per block: FM rows x all 512 gate cols. Panel p cols p*128..p*128+127.
// C-fragment (row,col) mapping identical across panels -> z/r/xh/hh co-located per lane.
__global__ __launch_bounds__(256) void gru_fused(
    const float* __restrict__ s0, const float* __restrict__ s1,
    const float* __restrict__ s2, const float* __restrict__ s3,
    const ushort_t* __restrict__ bth, const ushort_t* __restrict__ btl,
    const int K,
    const float* __restrict__ hcur, const float* __restrict__ b,  // (2,384) flat
    float* __restrict__ hout)
{
    __shared__ ushort_t Ah[2][FM * 32], Al[2][FM * 32];
    __shared__ ushort_t Bh[2][128 * 32], Bl[2][128 * 32];
    const float* srcs[4] = {s0, s1, s2, s3};
    const int tid = threadIdx.x;
    const int m0 = blockIdx.x * FM;
    const int w = tid >> 6, l = tid & 63;
    const int wc = w * 32;             // wave covers 32 cols of each panel
    const int l16 = l & 15, g = l >> 4;
    const int Kx = K - 128;

    const int ar = tid >> 2;           // A row 0..63 (only 0..31 used; tid<128 loads)
    const int kb = tid & 3;
    const bool aload = tid < 128;
    const int bw = w * 32;

    f32x4 acc[4][2][2];                // [panel][mf][nf] -- panel loop unrolled (static idx)
#pragma unroll
    for (int p = 0; p < 4; ++p)
#pragma unroll
        for (int i = 0; i < 2; ++i)
#pragma unroll
            for (int j = 0; j < 2; ++j) acc[p][i][j] = (f32x4){0.f, 0.f, 0.f, 0.f};

    float4 pv[2];
    auto issueA = [&](int kg) {
        const float* sp = srcs[kg >> 7] + (size_t)(m0 + ar) * H_ + (kg & 127) + kb * 8;
        pv[0] = reinterpret_cast<const float4*>(sp)[0];
        pv[1] = reinterpret_cast<const float4*>(sp)[1];
    };
    auto writeA = [&](int buf) {
        __align__(16) ushort_t hv[8], lv[8];
        split2(pv[0].x, hv[0], lv[0]); split2(pv[0].y, hv[1], lv[1]);
        split2(pv[0].z, hv[2], lv[2]); split2(pv[0].w, hv[3], lv[3]);
        split2(pv[1].x, hv[4], lv[4]); split2(pv[1].y, hv[5], lv[5]);
        split2(pv[1].z, hv[6], lv[6]); split2(pv[1].w, hv[7], lv[7]);
        const int p = (kb ^ ((ar >> 1) & 3)) * 8;
        *reinterpret_cast<ushort8*>(&Ah[buf][ar * 32 + p]) = *reinterpret_cast<ushort8*>(hv);
        *reinterpret_cast<ushort8*>(&Al[buf][ar * 32 + p]) = *reinterpret_cast<ushort8*>(lv);
    };
    auto stageB = [&](int buf, int pan, int k0) {
#pragma unroll
        for (int q = 0; q < 2; ++q) {
            const int row = bw + q * 16 + (l >> 2);
            const size_t off = (size_t)(pan * 128 + row) * K + k0 + (l & 3) * 8;
            __builtin_amdgcn_global_load_lds(
                (const __attribute__((address_space(1))) void*)(bth + off),
                (__attribute__((address_space(3))) void*)&Bh[buf][(bw + q * 16) * 32], 16, 0, 0);
            __builtin_amdgcn_global_load_lds(
                (const __attribute__((address_space(1))) void*)(btl + off),
                (__attribute__((address_space(3))) void*)&Bl[buf][(bw + q * 16) * 32], 16, 0, 0);
        }
    };

    int cur = 0;
#pragma unroll
    for (int p = 0; p < 4; ++p) {
        const int k_lo = (p == 3) ? Kx : 0;
        const int k_hi = (p == 2) ? Kx : K;
        if (aload) issueA(k_lo);
        stageB(cur, p, k_lo);
        if (aload) writeA(cur);
        for (int ks = k_lo; ks < k_hi; ks += 32) {
            __syncthreads();
            const bool more = (ks + 32 < k_hi);
            if (more) { if (aload) issueA(ks + 32); stageB(cur ^ 1, p, ks + 32); }
            // compute on buf `cur`
            {
                bf16x8 fah[2], fal[2], fbh[2], fbl[2];
#pragma unroll
                for (int mf = 0; mf < 2; ++mf) {
                    const int arow = mf * 16 + l16;
                    const int aoff = arow * 32 + ((g ^ ((arow >> 1) & 3)) * 8);
                    fah[mf] = *reinterpret_cast<const bf16x8*>(&Ah[cur][aoff]);
                    fal[mf] = *reinterpret_cast<const bf16x8*>(&Al[cur][aoff]);
                }
#pragma unroll
                for (int nf = 0; nf < 2; ++nf) {
                    const int brow = wc + nf * 16 + l16;
                    const int boff = brow * 32 + ((g ^ ((brow >> 1) & 3)) * 8);
                    fbh[nf] = *reinterpret_cast<const bf16x8*>(&Bh[cur][boff]);
                    fbl[nf] = *reinterpret_cast<const bf16x8*>(&Bl[cur][boff]);
                }
#pragma unroll
                for (int mf = 0; mf < 2; ++mf)
#pragma unroll
                    for (int nf = 0; nf < 2; ++nf)
                        acc[p][mf][nf] = __builtin_amdgcn_mfma_f32_16x16x32_bf16(fah[mf], fbh[nf], acc[p][mf][nf], 0, 0, 0);
#pragma unroll
                for (int mf = 0; mf < 2; ++mf)
#pragma unroll
                    for (int nf = 0; nf < 2; ++nf)
                        acc[p][mf][nf] = __builtin_amdgcn_mfma_f32_16x16x32_bf16(fal[mf], fbh[nf], acc[p][mf][nf], 0, 0, 0);
#pragma unroll
                for (int mf = 0; mf < 2; ++mf)
#pragma unroll
                    for (int nf = 0; nf < 2; ++nf)
                        acc[p][mf][nf] = __builtin_amdgcn_mfma_f32_16x16x32_bf16(fah[mf], fbl[nf], acc[p][mf][nf], 0, 0, 0);
            }
            if (more && aload) writeA(cur ^ 1);
            cur ^= 1;
        }
    }

    // in-register GRU gate math; C/D layout col=lane&15, row=(lane>>4)*4+reg
#pragma unroll
    for (int mf = 0; mf < 2; ++mf) {
#pragma unroll
        for (int nf = 0; nf < 2; ++nf) {
            const int col = wc + nf * 16 + l16;
            const float bz  = b[col] + b[384 + col];
            const float br  = b[128 + col] + b[512 + col];
            const float bxh = b[256 + col];
            const float bhh = b[640 + col];
            const int rbase = m0 + mf * 16 + g * 4;
#pragma unroll
            for (int r = 0; r < 4; ++r) {
                const int row = rbase + r;
                const float zp = acc[0][mf][nf][r] + bz;
                const float rp = acc[1][mf][nf][r] + br;
                const float xh = acc[2][mf][nf][r] + bxh;
                const float hh = acc[3][mf][nf][r] + bhh;
                const float z  = 1.f / (1.f + expf(-zp));
                const float rr = 1.f / (1.f + expf(-rp));
                const float cand = tanhf(xh + rr * hh);
                const float hv = hcur[(size_t)row * H_ + col];
                hout[(size_t)row * H_ + col] = z * hv + (1.f - z) * cand;
            }
        }
    }
}

// ---------------- host orchestration ----------------
extern "C" void kernel_launch(void* const* d_in, const int* in_sizes, int n_in,
                              void* d_out, int out_size, void* d_ws, size_t ws_size,
                              hipStream_t stream) {
    const float* states = (const float*)d_in[0];
    const int*   eids   = (const int*)  d_in[1];
    const float* tw     = (const float*)d_in[2];   // (4,T,H,H)
    const float* tb     = (const float*)d_in[3];   // (4,T,H)
    const float* gW[4]  = { (const float*)d_in[4],  (const float*)d_in[7],
                            (const float*)d_in[10], (const float*)d_in[13] };
    const float* gU[4]  = { (const float*)d_in[5],  (const float*)d_in[8],
                            (const float*)d_in[11], (const float*)d_in[14] };
    const float* gb[4]  = { (const float*)d_in[6],  (const float*)d_in[9],
                            (const float*)d_in[12], (const float*)d_in[15] };
    float* out = (float*)d_out;

    const int KL[4]   = {256, 384, 256, 512};              // IN_DIM + 128 per layer
    const size_t KOFF[4] = {0, 512ull*256, 512ull*(256+384), 512ull*(256+384+256)};
    const size_t BT_TOT  = 512ull * (256 + 384 + 256 + 512);   // 720896 ushorts
    const size_t WT_L    = (size_t)T_ * H_ * H_;               // per-layer W plane

    char* ws = (char*)d_ws;
    float* bufA = (float*)ws; ws += (size_t)BN_ * H_ * 4;
    float* bufB = (float*)ws; ws += (size_t)BN_ * H_ * 4;
    float* bufC = (float*)ws; ws += (size_t)BN_ * H_ * 4;   // final layer-0 state
    float* agg  = (float*)ws; ws += (size_t)BN_ * H_ * 4;
    float* msg  = (float*)ws; ws += (size_t)E_ * H_ * 4;    // 64 MB
    ushort_t* bthAll = (ushort_t*)ws; ws += BT_TOT * 2;
    ushort_t* btlAll = (ushort_t*)ws; ws += BT_TOT * 2;
    ushort_t* wthAll = (ushort_t*)ws; ws += 4 * WT_L * 2;   // (4,T,128,128) hi
    ushort_t* wtlAll = (ushort_t*)ws; ws += 4 * WT_L * 2;   // lo
    int*   perm  = (int*)ws;  ws += (size_t)E_ * 4;
    int*   rank  = (int*)ws;  ws += (size_t)E_ * 4;
    int*   tcnt  = (int*)ws;  ws += (size_t)BN_ * 4;
    int*   toff  = (int*)ws;  ws += (size_t)BN_ * 4;
    int*   tstart= (int*)ws;  ws += (size_t)(BN_ + 1) * 4;
    int*   meta  = (int*)ws;  ws += 64 * 4;

    // ---- one-time sorts + weight splits ----
    hipMemsetAsync(meta, 0, 40 * sizeof(int), stream);
    hipMemsetAsync(tcnt, 0, BN_ * sizeof(int), stream);
    count_all<<<(E_ + 255) / 256, 256, 0, stream>>>(eids, meta, tcnt);
    scan_types<<<1, 1, 0, stream>>>(meta);
    scan_tgt  <<<1, 256, 0, stream>>>(tcnt, tstart, toff);
    scatter_all<<<(E_ + 255) / 256, 256, 0, stream>>>(eids, meta, toff, perm, rank);
    for (int lyr = 0; lyr < 4; ++lyr) {
        int K = KL[lyr];
        build_bt<<<(512 * K + 255) / 256, 256, 0, stream>>>(
            gW[lyr], gU[lyr], K - 128, K, bthAll + KOFF[lyr], btlAll + KOFF[lyr]);
        build_wt<<<((int)WT_L + 255) / 256, 256, 0, stream>>>(
            tw + lyr * WT_L, wthAll + lyr * WT_L, wtlAll + lyr * WT_L);
    }

    // step schedule: layers [0,0,0, 1, 2,2,2, 3]
    const int layer_of[8] = {0, 0, 0, 1, 2, 2, 2, 3};
    float* target[8] = {bufA, bufB, bufC, bufA, bufB, bufA, bufB, out};

    const float* cur = states;
    const int edge_grid = E_ / EPB + T_;

    for (int s = 0; s < 8; ++s) {
        const int l = layer_of[s];
        edge_mfma<<<edge_grid, 256, 0, stream>>>(
            cur, eids, perm, rank, meta,
            wthAll + l * WT_L, wtlAll + l * WT_L, tb + (size_t)l * T_ * H_, msg);
        aggregate<<<BN_ / 2, 256, 0, stream>>>(msg, tstart, agg);

        const float* s0; const float* s1; const float* s2; const float* s3;
        if (l == 0 || l == 2)      { s0 = agg;    s1 = cur;  s2 = nullptr; s3 = nullptr; }
        else if (l == 1)           { s0 = states; s1 = agg;  s2 = cur;     s3 = nullptr; }
        else                       { s0 = states; s1 = bufC; s2 = agg;     s3 = cur;     }

        float* nxt = target[s];
        gru_fused<<<BN_ / FM, 256, 0, stream>>>(s0, s1, s2, s3,
                                                bthAll + KOFF[l], btlAll + KOFF[l],
                                                KL[l], cur, gb[l], nxt);
        cur = nxt;
    }
}